// Round 12
// baseline (2176.736 us; speedup 1.0000x reference)
//
#include <hip/hip_runtime.h>
#include <hip/hip_fp16.h>
#include <cstdint>
#include <algorithm>

// ---------------- problem constants ----------------
#define N1c 100000
#define N2c 80000
#define EPSc 1e-5f
#define STRIDE_N1 102400   // 100 blocks of 1024 (>= N1+1 bins)
#define STRIDE_N2 81920    // 80 blocks of 1024  (>= N2+1 bins)

typedef _Float16 fp16x8 __attribute__((ext_vector_type(8)));
typedef float f32x4 __attribute__((ext_vector_type(4)));

// ---------------- CSR build: one pass for ALL k-chunks of a layer ----------
__global__ __launch_bounds__(256) void rank2d_kernel(
    const int* __restrict__ out_idx, int* __restrict__ rank,
    int* __restrict__ bins, int E, int M, int q, int stride)
{
    for (int e = blockIdx.x * 256 + threadIdx.x; e < E; e += gridDim.x * 256) {
        int chunk = (e / M) / q;
        rank[e] = atomicAdd(&bins[chunk * stride + out_idx[e]], 1);
    }
}

__global__ __launch_bounds__(256) void scan1(
    const int* __restrict__ bins, int* __restrict__ ptr,
    int* __restrict__ bsums, int n)
{
    __shared__ int lds[256];
    int base = blockIdx.x * 1024;
    int v[4]; int t = 0;
    #pragma unroll
    for (int i = 0; i < 4; ++i) {
        int idx = base + threadIdx.x * 4 + i;
        v[i] = idx < n ? bins[idx] : 0;
        t += v[i];
    }
    lds[threadIdx.x] = t; __syncthreads();
    for (int off = 1; off < 256; off <<= 1) {
        int x = threadIdx.x >= off ? lds[threadIdx.x - off] : 0;
        __syncthreads();
        lds[threadIdx.x] += x;
        __syncthreads();
    }
    int run = lds[threadIdx.x] - t;
    if (threadIdx.x == 255) bsums[blockIdx.x] = lds[255];
    #pragma unroll
    for (int i = 0; i < 4; ++i) {
        int idx = base + threadIdx.x * 4 + i;
        if (idx < n) ptr[idx] = run;
        run += v[i];
    }
}

// serial exclusive scan of block sums, carry reset at chunk boundaries
__global__ __launch_bounds__(64) void scan2s(
    int* __restrict__ bsums, int bpc, int nch)
{
    int c = threadIdx.x;
    if (c < nch) {
        int run = 0;
        for (int i = 0; i < bpc; ++i) {
            int idx = c * bpc + i;
            int t = bsums[idx]; bsums[idx] = run; run += t;
        }
    }
}

__global__ __launch_bounds__(256) void scan3(
    int* __restrict__ ptr, const int* __restrict__ bsums, int n)
{
    int idx = blockIdx.x * 1024 + threadIdx.x * 4;
    int add = bsums[blockIdx.x];
    #pragma unroll
    for (int i = 0; i < 4; ++i)
        if (idx + i < n) ptr[idx + i] += add;
}

// ---------------- W pre-convert: Wh[k][c][j] = (fp16) W[k][j][c] ----------
__global__ __launch_bounds__(256) void wconv_fp16(
    const float* __restrict__ W, _Float16* __restrict__ Wh,
    int K, int CIN, int CTILE, int WST, int total)
{
    for (int idx = blockIdx.x * 256 + threadIdx.x; idx < total;
         idx += gridDim.x * 256) {
        int k = idx / (CTILE * CIN);
        int c = (idx / CIN) % CTILE;
        int j = idx % CIN;
        Wh[idx] = (_Float16)W[(size_t)k * CIN * WST + (size_t)j * WST + c];
    }
}

// ---------------- conv1a special: scatter (x_val, k) 8B per edge ----------
__global__ __launch_bounds__(256) void scatter_1a(
    const float* __restrict__ x, const int* __restrict__ iin,
    const int* __restrict__ iout, const int* __restrict__ ptr,
    const int* __restrict__ rank, float2* __restrict__ payload, int E, int M)
{
    for (int e = blockIdx.x * 256 + threadIdx.x; e < E; e += gridDim.x * 256) {
        int k = e / M;
        float2 p; p.x = x[iin[e]]; p.y = __int_as_float(k);
        payload[ptr[iout[e]] + rank[e]] = p;
    }
}

// out[o][c] = relu( sum_e val_e * W[k_e][c] ), W (125x32) in LDS, fp16 out
__global__ __launch_bounds__(256) void phaseB_1a(
    const float2* __restrict__ payload, const int* __restrict__ ptr,
    const float* __restrict__ W, __half* __restrict__ out, int n)
{
    __shared__ float Wl[125 * 32];
    for (int i = threadIdx.x; i < 125 * 32; i += 256) Wl[i] = W[i];
    __syncthreads();
    int total = n * 32;
    for (int idx = blockIdx.x * 256 + threadIdx.x; idx < total; idx += gridDim.x * 256) {
        int o = idx >> 5, c = idx & 31;
        int s0 = ptr[o], s1 = ptr[o + 1];
        float acc = 0.f;
        for (int s = s0; s < s1; ++s) {
            float2 p = payload[s];
            acc = fmaf(p.x, Wl[(__float_as_int(p.y) << 5) + c], acc);
        }
        out[idx] = __float2half(fmaxf(acc, 0.f));
    }
}

// ---------------- Phase A: MFMA gather-GEMM, PP=64, W in LDS -------------
// C[64 pairs][CTILE] = G[64][CIN] x Wt^T via mfma_f32_16x16x32_f16.
// r6-verified lane layout; r8-verified structure (Wt staged once per block
// from pre-converted fp16 Wh; r7's B-from-global caused an L2 storm).
// GMODE: 0 plain, 2 BN(scale/shift fp32)+ReLU at gather. Contrib fp16.
template <int CIN, int CTILE, int GMODE, int IN16>
__global__ __launch_bounds__(256, 3) void phaseA_mfma(
    const void* __restrict__ feats_, const _Float16* __restrict__ Wh,
    const int* __restrict__ in_idx, const int* __restrict__ out_idx,
    const int* __restrict__ ptr, const int* __restrict__ rank,
    __half* __restrict__ contrib, int M,
    const float* __restrict__ sc, const float* __restrict__ sh)
{
    constexpr int PP  = 64;              // pairs per block
    constexpr int NK  = CIN / 32;        // K-steps
    constexpr int NCF = CTILE / 16;      // col fragments
    constexpr int GCHK = CIN / 8;        // fp16x8 chunks per row
    constexpr int GSM  = (GCHK < 16 ? GCHK : 16) - 1;
    constexpr int RCH  = GCHK / 4;       // chunks per stager thread (>=1)
    static_assert(CIN % 32 == 0 && CTILE % 16 == 0 && RCH >= 1, "");

    __shared__ __align__(16) _Float16 Gl[PP * CIN];
    __shared__ __align__(16) _Float16 Wt[CTILE * CIN];
    __shared__ int sslot[PP];

    const int tid  = threadIdx.x;
    const int wave = tid >> 6;
    const int lane = tid & 63;
    const int k    = blockIdx.y;

    const int* iin  = in_idx  + (size_t)k * M;
    const int* iout = out_idx + (size_t)k * M;
    const int* rk   = rank    + (size_t)k * M;
    const _Float16* Wk = Wh + (size_t)k * CTILE * CIN;

    // ---- stage Wt ONCE per block (base-invariant), swizzled ----
    for (int i = tid; i < CTILE * GCHK; i += 256) {
        int row = i / GCHK, ch = i % GCHK;
        fp16x8 v = *(const fp16x8*)&Wk[(size_t)row * CIN + ch * 8];
        *(fp16x8*)&Wt[row * CIN + ((ch ^ (row & GSM)) << 3)] = v;
    }

    for (int base = blockIdx.x * PP; base < M; base += gridDim.x * PP) {
        if (tid < PP && base + tid < M)
            sslot[tid] = ptr[iout[base + tid]] + rk[base + tid];

        // ---- stage G: 4 threads per pair-row, swizzled 16B writes ----
        {
            int r = tid & 63;
            int h = tid >> 6;                // quarter of the row
            int p = base + r;
            if (p < M) {
                const int c0 = h * (CIN / 4);
                if (IN16) {
                    const _Float16* fr =
                        (const _Float16*)feats_ + (size_t)iin[p] * CIN + c0;
                    #pragma unroll
                    for (int cc = 0; cc < RCH; ++cc) {
                        int c = cc * 8;
                        fp16x8 v = *(const fp16x8*)(fr + c);
                        if (GMODE == 2) {
                            #pragma unroll
                            for (int j = 0; j < 8; ++j) {
                                float x = fmaf((float)v[j], sc[c0 + c + j],
                                               sh[c0 + c + j]);
                                v[j] = (_Float16)fmaxf(x, 0.f);
                            }
                        }
                        int ch = (c0 + c) >> 3;
                        *(fp16x8*)&Gl[r * CIN + ((ch ^ (r & GSM)) << 3)] = v;
                    }
                } else {
                    const float* fr =
                        (const float*)feats_ + (size_t)iin[p] * CIN + c0;
                    #pragma unroll
                    for (int cc = 0; cc < RCH; ++cc) {
                        int c = cc * 8;
                        float a[8];
                        *(float4*)&a[0] = *(const float4*)(fr + c);
                        *(float4*)&a[4] = *(const float4*)(fr + c + 4);
                        if (GMODE == 2) {
                            #pragma unroll
                            for (int j = 0; j < 8; ++j)
                                a[j] = fmaxf(fmaf(a[j], sc[c0 + c + j],
                                                  sh[c0 + c + j]), 0.f);
                        }
                        fp16x8 v;
                        #pragma unroll
                        for (int j = 0; j < 8; ++j) v[j] = (_Float16)a[j];
                        int ch = (c0 + c) >> 3;
                        *(fp16x8*)&Gl[r * CIN + ((ch ^ (r & GSM)) << 3)] = v;
                    }
                }
            }
        }
        __syncthreads();

        // ---- MFMA: wave owns 16 rows (wave*16), all CTILE cols ----
        f32x4 acc[NCF];
        #pragma unroll
        for (int cf = 0; cf < NCF; ++cf)
            acc[cf] = (f32x4){0.f, 0.f, 0.f, 0.f};

        const int lrow = lane & 15;
        const int lk8  = (lane >> 4) * 8;
        #pragma unroll
        for (int kk = 0; kk < NK; ++kk) {
            int col = kk * 32 + lk8;
            int r = wave * 16 + lrow;
            fp16x8 afr = *(const fp16x8*)
                &Gl[r * CIN + ((((col >> 3) ^ (r & GSM))) << 3)];
            #pragma unroll
            for (int cf = 0; cf < NCF; ++cf) {
                int rw = cf * 16 + lrow;
                fp16x8 bfr = *(const fp16x8*)
                    &Wt[rw * CIN + ((((col >> 3) ^ (rw & GSM))) << 3)];
                acc[cf] = __builtin_amdgcn_mfma_f32_16x16x32_f16(
                    afr, bfr, acc[cf], 0, 0, 0);
            }
        }

        // ---- epilogue: scatter rows via sslot, fp32->fp16 ----
        {
            int prb = wave * 16 + (lane >> 4) * 4;
            #pragma unroll
            for (int b = 0; b < 4; ++b) {
                int pr = prb + b;
                if (base + pr < M) {
                    size_t s = (size_t)sslot[pr];
                    #pragma unroll
                    for (int cf = 0; cf < NCF; ++cf)
                        contrib[s * CTILE + cf * 16 + lrow] =
                            __float2half(acc[cf][b]);
                }
            }
        }
        __syncthreads();
    }
}

// ---------------- Phase A for conv3b: dual cout-half, gather h3 ONCE -----
// Stages Gl (64x128 fp16) once per tile; loops half in {0,1} reloading only
// Wt (128x128, 32KB). Writes 256-wide contrib rows (r11-verified).
template <int GMODE>
__global__ __launch_bounds__(256, 3) void phaseA_mfma_3b(
    const void* __restrict__ feats_, const _Float16* __restrict__ Wh,
    const int* __restrict__ in_idx, const int* __restrict__ out_idx,
    const int* __restrict__ ptr, const int* __restrict__ rank,
    __half* __restrict__ contrib, int M,
    const float* __restrict__ sc, const float* __restrict__ sh)
{
    constexpr int CIN = 128, PP = 64, NK = 4, NCF = 8;
    constexpr int GCHK = 16, GSM = 15, RCH = 4;

    __shared__ __align__(16) _Float16 Gl[PP * CIN];     // 16KB
    __shared__ __align__(16) _Float16 Wt[128 * CIN];    // 32KB
    __shared__ int sslot[PP];

    const int tid  = threadIdx.x;
    const int wave = tid >> 6;
    const int lane = tid & 63;
    const int k    = blockIdx.y;

    const _Float16* feats = (const _Float16*)feats_;
    const int* iin  = in_idx  + (size_t)k * M;
    const int* iout = out_idx + (size_t)k * M;
    const int* rk   = rank    + (size_t)k * M;
    const _Float16* Wk = Wh + (size_t)k * 256 * CIN;    // [256 couts][128]

    const int lrow = lane & 15;
    const int lk8  = (lane >> 4) * 8;

    for (int base = blockIdx.x * PP; base < M; base += gridDim.x * PP) {
        if (tid < PP && base + tid < M)
            sslot[tid] = ptr[iout[base + tid]] + rk[base + tid];

        // ---- stage G once (IN16 + BN at gather) ----
        {
            int r = tid & 63;
            int h = tid >> 6;
            int p = base + r;
            if (p < M) {
                const int c0 = h * 32;
                const _Float16* fr = feats + (size_t)iin[p] * CIN + c0;
                #pragma unroll
                for (int cc = 0; cc < RCH; ++cc) {
                    int c = cc * 8;
                    fp16x8 v = *(const fp16x8*)(fr + c);
                    if (GMODE == 2) {
                        #pragma unroll
                        for (int j = 0; j < 8; ++j) {
                            float x = fmaf((float)v[j], sc[c0 + c + j],
                                           sh[c0 + c + j]);
                            v[j] = (_Float16)fmaxf(x, 0.f);
                        }
                    }
                    int ch = (c0 + c) >> 3;
                    *(fp16x8*)&Gl[r * CIN + ((ch ^ (r & GSM)) << 3)] = v;
                }
            }
        }

        #pragma unroll
        for (int half = 0; half < 2; ++half) {
            __syncthreads();   // Gl ready / previous half's MFMA done with Wt
            // stage Wt for this half (rows half*128 .. half*128+127)
            for (int i = tid; i < 128 * GCHK; i += 256) {
                int row = i / GCHK, ch = i % GCHK;
                fp16x8 v = *(const fp16x8*)
                    &Wk[(size_t)(half * 128 + row) * CIN + ch * 8];
                *(fp16x8*)&Wt[row * CIN + ((ch ^ (row & GSM)) << 3)] = v;
            }
            __syncthreads();

            f32x4 acc[NCF];
            #pragma unroll
            for (int cf = 0; cf < NCF; ++cf)
                acc[cf] = (f32x4){0.f, 0.f, 0.f, 0.f};

            #pragma unroll
            for (int kk = 0; kk < NK; ++kk) {
                int col = kk * 32 + lk8;
                int r = wave * 16 + lrow;
                fp16x8 afr = *(const fp16x8*)
                    &Gl[r * CIN + ((((col >> 3) ^ (r & GSM))) << 3)];
                #pragma unroll
                for (int cf = 0; cf < NCF; ++cf) {
                    int rw = cf * 16 + lrow;
                    fp16x8 bfr = *(const fp16x8*)
                        &Wt[rw * CIN + ((((col >> 3) ^ (rw & GSM))) << 3)];
                    acc[cf] = __builtin_amdgcn_mfma_f32_16x16x32_f16(
                        afr, bfr, acc[cf], 0, 0, 0);
                }
            }

            // epilogue: scatter 256-wide rows via sslot
            int prb = wave * 16 + (lane >> 4) * 4;
            #pragma unroll
            for (int b = 0; b < 4; ++b) {
                int pr = prb + b;
                if (base + pr < M) {
                    size_t s = (size_t)sslot[pr];
                    #pragma unroll
                    for (int cf = 0; cf < NCF; ++cf)
                        contrib[s * 256 + half * 128 + cf * 16 + lrow] =
                            __float2half(acc[cf][b]);
                }
            }
        }
        __syncthreads();
    }
}

// ---------------- Phase B: V=4-vectorized segmented sum ----------------
// Each thread owns 4 consecutive channels; contrib loads are 2x half2 (8B).
// OUT16=1: fp16 out (intermediates / partial buffers); 0: fp32 out.
// PARTIN=1: accum source is a separate tight fp16 buffer part_in[o*CSTR+c]
// (the multi-chunk partial), independent of the out type.
// STATS: per-thread 4-channel fp64 sums, TPR-aligned LDS tree reduction
// (TPR = CSTR/4 divides all offsets 128..TPR since TPR in {8,16,32,64}).
template <int CSTR, bool STATS, int OUT16, int PARTIN>
__global__ __launch_bounds__(256) void phaseB8(
    const __half* __restrict__ contrib, const int* __restrict__ ptr,
    void* __restrict__ out_, const __half* __restrict__ part_in,
    int n, int ostr, int accum,
    double* __restrict__ statsbuf, int sqoff)
{
    constexpr int V = 4;
    constexpr int TPR = CSTR / V;
    static_assert(CSTR % 4 == 0 && 256 % TPR == 0, "");
    float s1[V] = {0.f, 0.f, 0.f, 0.f}, s2[V] = {0.f, 0.f, 0.f, 0.f};
    int total = n * TPR;
    for (int idx = blockIdx.x * 256 + threadIdx.x; idx < total;
         idx += gridDim.x * 256) {
        int o  = idx / TPR;
        int c0 = (idx % TPR) * V;
        int a = ptr[o], b = ptr[o + 1];
        size_t obase = (size_t)o * ostr + c0;
        float acc[V];
        if (accum) {
            if (PARTIN) {
                const __half2* pp =
                    (const __half2*)(part_in + (size_t)o * CSTR + c0);
                __half2 p0 = pp[0], p1 = pp[1];
                acc[0] = __low2float(p0); acc[1] = __high2float(p0);
                acc[2] = __low2float(p1); acc[3] = __high2float(p1);
            } else if (OUT16) {
                const __half2* pp = (const __half2*)((const __half*)out_ + obase);
                __half2 p0 = pp[0], p1 = pp[1];
                acc[0] = __low2float(p0); acc[1] = __high2float(p0);
                acc[2] = __low2float(p1); acc[3] = __high2float(p1);
            } else {
                float4 f = *(const float4*)((const float*)out_ + obase);
                acc[0] = f.x; acc[1] = f.y; acc[2] = f.z; acc[3] = f.w;
            }
        } else {
            #pragma unroll
            for (int j = 0; j < V; ++j) acc[j] = 0.f;
        }
        for (int s = a; s < b; ++s) {
            const __half2* cp =
                (const __half2*)(contrib + (size_t)s * CSTR + c0);
            __half2 q0 = cp[0], q1 = cp[1];
            acc[0] += __low2float(q0); acc[1] += __high2float(q0);
            acc[2] += __low2float(q1); acc[3] += __high2float(q1);
        }
        if (OUT16) {
            __half2 h0 = __floats2half2_rn(acc[0], acc[1]);
            __half2 h1 = __floats2half2_rn(acc[2], acc[3]);
            uint2 pk;
            pk.x = *(unsigned int*)&h0;
            pk.y = *(unsigned int*)&h1;
            *(uint2*)((__half*)out_ + obase) = pk;
        } else {
            float4 f;
            f.x = acc[0]; f.y = acc[1]; f.z = acc[2]; f.w = acc[3];
            *(float4*)((float*)out_ + obase) = f;
        }
        if (STATS) {
            #pragma unroll
            for (int j = 0; j < V; ++j) {
                s1[j] += acc[j];
                s2[j] += acc[j] * acc[j];
            }
        }
    }
    if constexpr (STATS) {
        __shared__ double l1[256][V], l2[256][V];
        #pragma unroll
        for (int j = 0; j < V; ++j) {
            l1[threadIdx.x][j] = (double)s1[j];
            l2[threadIdx.x][j] = (double)s2[j];
        }
        __syncthreads();
        for (int off = 128; off >= TPR; off >>= 1) {
            if (threadIdx.x < (unsigned)off) {
                #pragma unroll
                for (int j = 0; j < V; ++j) {
                    l1[threadIdx.x][j] += l1[threadIdx.x + off][j];
                    l2[threadIdx.x][j] += l2[threadIdx.x + off][j];
                }
            }
            __syncthreads();
        }
        if (threadIdx.x < TPR) {
            #pragma unroll
            for (int j = 0; j < V; ++j) {
                atomicAdd(&statsbuf[threadIdx.x * V + j], l1[threadIdx.x][j]);
                atomicAdd(&statsbuf[sqoff + threadIdx.x * V + j],
                          l2[threadIdx.x][j]);
            }
        }
    }
}

// ---------------- BN helpers (fp64 stats) ----------------
template <int C>
__global__ __launch_bounds__(256) void make_scsh(
    const double* __restrict__ sums, const float* __restrict__ g,
    const float* __restrict__ b, float* __restrict__ sc, float* __restrict__ sh,
    double inv_n)
{
    int c = threadIdx.x;
    if (c < C) {
        double mean = sums[c] * inv_n;
        double var  = sums[C + c] * inv_n - mean * mean;
        float s = g[c] * (float)(1.0 / sqrt(var + (double)EPSc));
        sc[c] = s;
        sh[c] = b[c] - (float)mean * s;
    }
}

template <int C>
__global__ __launch_bounds__(256) void bn_apply_relu_kernel(
    float* __restrict__ x, int n, const double* __restrict__ sums,
    const float* __restrict__ g, const float* __restrict__ b)
{
    const int c = threadIdx.x % C;
    const double inv_n = 1.0 / (double)n;
    double mean = sums[c] * inv_n;
    double var  = sums[C + c] * inv_n - mean * mean;
    float scale = g[c] * (float)(1.0 / sqrt(var + (double)EPSc));
    float shift = b[c] - (float)mean * scale;
    size_t total = (size_t)n * C;
    size_t stride = (size_t)gridDim.x * 256;
    for (size_t i = (size_t)blockIdx.x * 256 + threadIdx.x; i < total; i += stride)
        x[i] = fmaxf(x[i] * scale + shift, 0.f);
}

// Variant that also writes an fp16 shadow copy (for the next layer's gather).
template <int C>
__global__ __launch_bounds__(256) void bn_apply_relu_shadow_kernel(
    float* __restrict__ x, __half* __restrict__ xh, int n,
    const double* __restrict__ sums,
    const float* __restrict__ g, const float* __restrict__ b)
{
    const int c = threadIdx.x % C;
    const double inv_n = 1.0 / (double)n;
    double mean = sums[c] * inv_n;
    double var  = sums[C + c] * inv_n - mean * mean;
    float scale = g[c] * (float)(1.0 / sqrt(var + (double)EPSc));
    float shift = b[c] - (float)mean * scale;
    size_t total = (size_t)n * C;
    size_t stride = (size_t)gridDim.x * 256;
    for (size_t i = (size_t)blockIdx.x * 256 + threadIdx.x; i < total; i += stride) {
        float v = fmaxf(x[i] * scale + shift, 0.f);
        x[i] = v;
        xh[i] = __float2half(v);
    }
}

// ---------------- host-side helpers ----------------
struct Plan { int q, nch; };

static Plan make_plan(long long tot_elems, int K, long long cap, int maxch)
{
    if (cap < 1) cap = 1;
    long long nch0 = (tot_elems + cap - 1) / cap;
    if (nch0 < 1) nch0 = 1;
    if (nch0 > K) nch0 = K;
    int q = (int)((K + nch0 - 1) / nch0);
    int nch = (K + q - 1) / q;
    if (nch > maxch) { q = (K + maxch - 1) / maxch; nch = (K + q - 1) / q; }
    return { q, nch };
}

static void build_csr2d(const int* iout, int* rank, int* bins, int* ptr, int* bsums,
                        int E, int M, int q, int nch, int stride, hipStream_t s)
{
    hipMemsetAsync(bins, 0, (size_t)nch * stride * sizeof(int), s);
    int gb = std::min(2048, (E + 255) / 256);
    hipLaunchKernelGGL(rank2d_kernel, dim3(gb), dim3(256), 0, s, iout, rank, bins, E, M, q, stride);
    int totalbins = nch * stride, nb = totalbins / 1024, bpc = stride / 1024;
    hipLaunchKernelGGL(scan1, dim3(nb), dim3(256), 0, s, bins, ptr, bsums, totalbins);
    hipLaunchKernelGGL(scan2s, dim3(1), dim3(64), 0, s, bsums, bpc, nch);
    hipLaunchKernelGGL(scan3, dim3(nb), dim3(256), 0, s, ptr, bsums, totalbins);
}

// One full layer (no cout split): k-chunked as needed.
template <int CIN, int COUT, int GMODE, bool STATS, int IN16, int OUT16>
static void run_layer(const void* feats, const float* W,
                      const int* iin, const int* iout, void* outp,
                      int M, int K, int n_out, int stride, int maxch,
                      int* bins, int* ptr, int* bsums, int* rank, __half* contrib,
                      _Float16* wh, long long cap_f32,
                      const float* sc, const float* sh,
                      double* statsbuf, hipStream_t s)
{
    int wtot = K * COUT * CIN;
    hipLaunchKernelGGL(wconv_fp16, dim3(std::min(2048, (wtot + 255) / 256)),
                       dim3(256), 0, s, W, wh, K, CIN, COUT, COUT, wtot);
    long long cap_h = cap_f32 * 2;
    Plan pl = make_plan((long long)K * M * COUT, K, cap_h, maxch);
    build_csr2d(iout, rank, bins, ptr, bsums, K * M, M, pl.q, pl.nch, stride, s);
    for (int ch = 0; ch < pl.nch; ++ch) {
        int k0 = ch * pl.q;
        int qc = std::min(pl.q, K - k0);
        dim3 g((M + 63) / 64, qc);
        hipLaunchKernelGGL((phaseA_mfma<CIN, COUT, GMODE, IN16>), g, dim3(256), 0, s,
                           feats, wh + (size_t)k0 * COUT * CIN,
                           iin + (size_t)k0 * M, iout + (size_t)k0 * M,
                           ptr + (size_t)ch * stride, rank + (size_t)k0 * M,
                           contrib, M, sc, sh);
        bool last = (ch == pl.nch - 1);
        if (STATS && last)
            hipLaunchKernelGGL((phaseB8<COUT, true, OUT16, 0>), dim3(2048), dim3(256), 0, s,
                               contrib, ptr + (size_t)ch * stride, outp,
                               (const __half*)nullptr, n_out, COUT,
                               ch ? 1 : 0, statsbuf, COUT);
        else
            hipLaunchKernelGGL((phaseB8<COUT, false, OUT16, 0>), dim3(2048), dim3(256), 0, s,
                               contrib, ptr + (size_t)ch * stride, outp,
                               (const __half*)nullptr, n_out, COUT,
                               ch ? 1 : 0, (double*)nullptr, 0);
    }
}

extern "C" void kernel_launch(void* const* d_in, const int* in_sizes, int n_in,
                              void* d_out, int out_size, void* d_ws, size_t ws_size,
                              hipStream_t stream)
{
    const float* x_feats = (const float*)d_in[0];
    const float* w1a = (const float*)d_in[1];
    const float* w1b = (const float*)d_in[2];
    const float* w1c = (const float*)d_in[3];
    const float* w2  = (const float*)d_in[4];
    const float* w3a = (const float*)d_in[5];
    const float* w3b = (const float*)d_in[6];
    const float* bn1b_g = (const float*)d_in[7];
    const float* bn1b_b = (const float*)d_in[8];
    const float* bn1c_g = (const float*)d_in[9];
    const float* bn1c_b = (const float*)d_in[10];
    const float* bn3a_g = (const float*)d_in[11];
    const float* bn3a_b = (const float*)d_in[12];
    const float* bn3b_g = (const float*)d_in[13];
    const float* bn3b_b = (const float*)d_in[14];
    const int* km1a_in  = (const int*)d_in[15];
    const int* km1a_out = (const int*)d_in[16];
    const int* km1b_in  = (const int*)d_in[17];
    const int* km1b_out = (const int*)d_in[18];
    const int* km1c_in  = (const int*)d_in[19];
    const int* km1c_out = (const int*)d_in[20];
    const int* km2_in   = (const int*)d_in[21];
    const int* km2_out  = (const int*)d_in[22];
    const int* km3a_in  = (const int*)d_in[23];
    const int* km3a_out = (const int*)d_in[24];
    const int* km3b_in  = (const int*)d_in[25];
    const int* km3b_out = (const int*)d_in[26];

    float* out  = (float*)d_out;
    float* x_e1 = out;                       // [N1,32] fp32 (final)
    float* x_e2 = out + (size_t)N1c * 32;    // [N2,256] fp32 (final)

    // ---- workspace layout (float-element offsets, 16B-aligned) ----
    float* ws = (float*)d_ws;
    float*  poolA  = ws;                        // 10,240,000 (h1 -> h3, fp16)
    float*  poolB  = poolA + 10240000;          //  5,120,000 (h2 -> h2b+xe1h)
    double* dstats = (double*)(poolB + 5120000);//  2,048 doubles
    float*  scsh   = (float*)(dstats + 2048);   //  1,024
    int*    bins   = (int*)(scsh + 1024);       //  819,200
    int*    ptr    = bins + 819200;             //  819,200
    int*    bsums  = ptr + 819200;              //  1,024
    int*    rank   = bsums + 1024;              //  2,500,000
    float*  whf    = (float*)(rank + 2500000);  //  442,400 (fp16 W^T buffer)
    _Float16* wh   = (_Float16*)whf;
    float*  contribf = whf + 442400;
    __half* contrib  = (__half*)contribf;
    const long long FIXED = 10240000LL + 5120000 + 4096 + 1024
                          + 819200 + 819200 + 1024 + 2500000 + 442400;
    long long cap = (long long)(ws_size / 4) - FIXED - 32;   // fp32 elems left
    if (cap < 1) cap = 1;

    __half* h1  = (__half*)poolA;   // [N1,32] fp16
    __half* h3  = (__half*)poolA;   // [N2,128] fp16 = poolA floats [0,5.12M)
    __half* h2  = (__half*)poolB;   // [N1,32] fp16
    __half* h2b = (__half*)poolB;   // [N2,64] fp16 (h2 dead by then)
    __half* xe1h = (__half*)poolB + 5120000;  // [N1,32] fp16 shadow of x_e1
    // conv3b partial buffer: 80000*256 fp16 = 20.48M halfs = 10.24M floats,
    // overlaid on poolA floats [5.12M,10.24M) + all of poolB — all dead by
    // conv3b (h1/h2/h2b/xe1h consumed; h3 occupies only poolA [0,5.12M)).
    __half* xpart = (__half*)(poolA + 5120000);

    double* dst1b = dstats;
    double* dst1c = dstats + 512;
    double* dst3a = dstats + 1024;
    double* dst3b = dstats + 1536;
    float* sc1b = scsh,       *sh1b = scsh + 32;
    float* sc3a = scsh + 256, *sh3a = scsh + 384;

    hipMemsetAsync(dstats, 0, 2048 * sizeof(double), stream);

    // ---- conv1a (1->32, K=125) + ReLU: scatter (val,k) + W-in-LDS reduce ----
    {
        build_csr2d(km1a_out, rank, bins, ptr, bsums, 125 * 20000, 20000, 125, 1,
                    STRIDE_N1, stream);
        hipLaunchKernelGGL(scatter_1a, dim3(2048), dim3(256), 0, stream,
                           x_feats, km1a_in, km1a_out, ptr, rank, (float2*)contribf,
                           125 * 20000, 20000);
        hipLaunchKernelGGL(phaseB_1a, dim3(2048), dim3(256), 0, stream,
                           (const float2*)contribf, ptr, w1a, h1, N1c);
    }

    // ---- conv1b (32->32, K=125): fp16 in/out + fp64 stats; BN fused later ----
    run_layer<32, 32, 0, true, 1, 1>(h1, w1b, km1b_in, km1b_out, h2, 20000, 125, N1c,
                                     STRIDE_N1, 8, bins, ptr, bsums, rank, contrib,
                                     wh, cap, nullptr, nullptr, dst1b, stream);
    hipLaunchKernelGGL((make_scsh<32>), dim3(1), dim3(256), 0, stream,
                       dst1b, bn1b_g, bn1b_b, sc1b, sh1b, 1.0 / N1c);

    // ---- conv1c (32->32, K=125): BN(h2)+ReLU at gather; x_e1 fp32 + stats ----
    run_layer<32, 32, 2, true, 1, 0>(h2, w1c, km1c_in, km1c_out, x_e1, 20000, 125, N1c,
                                     STRIDE_N1, 8, bins, ptr, bsums, rank, contrib,
                                     wh, cap, sc1b, sh1b, dst1c, stream);
    // BN+ReLU on x_e1 (final fp32) + fp16 shadow for conv2's gather
    hipLaunchKernelGGL((bn_apply_relu_shadow_kernel<32>), dim3(2048), dim3(256), 0, stream,
                       x_e1, xe1h, N1c, dst1c, bn1c_g, bn1c_b);

    // ---- conv2 (32->64, K=27): fp16 in (xe1h), fp16 out, no activation ----
    run_layer<32, 64, 0, false, 1, 1>(xe1h, w2, km2_in, km2_out, h2b, 30000, 27, N2c,
                                      STRIDE_N2, 10, bins, ptr, bsums, rank, contrib,
                                      wh, cap, nullptr, nullptr, nullptr, stream);

    // ---- conv3a (64->128, K=27): fp16 in/out + stats; BN fused at conv3b ----
    run_layer<64, 128, 0, true, 1, 1>(h2b, w3a, km3a_in, km3a_out, h3, 20000, 27, N2c,
                                      STRIDE_N2, 10, bins, ptr, bsums, rank, contrib,
                                      wh, cap, nullptr, nullptr, dst3a, stream);
    hipLaunchKernelGGL((make_scsh<128>), dim3(1), dim3(256), 0, stream,
                       dst3a, bn3a_g, bn3a_b, sc3a, sh3a, 1.0 / N2c);

    // ---- conv3b (128->256, K=27): dual-half phaseA (gather h3 once) ----
    // Multi-chunk phaseB accumulates through a fp16 partial (xpart): non-last
    // passes write fp16 (halves the wasted HBM writes of the fp32 accum);
    // the last pass reads the partial (L3-hot) and writes final fp32 + stats.
    {
        const int M = 20000, K = 27;
        int wtot = K * 256 * 128;
        hipLaunchKernelGGL(wconv_fp16, dim3(2048), dim3(256), 0, stream,
                           w3b, wh, K, 128, 256, 256, wtot);
        Plan pl = make_plan((long long)K * M * 256, K, cap * 2, 10);
        build_csr2d(km3b_out, rank, bins, ptr, bsums, K * M, M, pl.q, pl.nch,
                    STRIDE_N2, stream);
        for (int ch = 0; ch < pl.nch; ++ch) {
            int k0 = ch * pl.q;
            int qc = std::min(pl.q, K - k0);
            dim3 g((M + 63) / 64, qc);
            hipLaunchKernelGGL((phaseA_mfma_3b<2>), g, dim3(256), 0, stream,
                               (const void*)h3, wh + (size_t)k0 * 256 * 128,
                               km3b_in + (size_t)k0 * M, km3b_out + (size_t)k0 * M,
                               ptr + (size_t)ch * STRIDE_N2, rank + (size_t)k0 * M,
                               contrib, M, sc3a, sh3a);
            bool last = (ch == pl.nch - 1);
            if (!last)
                // partial pass: fp16 out to xpart (accum from xpart if ch>0)
                hipLaunchKernelGGL((phaseB8<256, false, 1, 0>), dim3(2048), dim3(256), 0, stream,
                                   contrib, ptr + (size_t)ch * STRIDE_N2,
                                   xpart, (const __half*)nullptr, N2c, 256,
                                   ch ? 1 : 0, (double*)nullptr, 0);
            else if (ch == 0)
                // single-chunk case: direct fp32 + stats
                hipLaunchKernelGGL((phaseB8<256, true, 0, 0>), dim3(2048), dim3(256), 0, stream,
                                   contrib, ptr + (size_t)ch * STRIDE_N2,
                                   x_e2, (const __half*)nullptr, N2c, 256,
                                   0, dst3b, 256);
            else
                // final pass: accum from fp16 partial, write fp32 + stats
                hipLaunchKernelGGL((phaseB8<256, true, 0, 1>), dim3(2048), dim3(256), 0, stream,
                                   contrib, ptr + (size_t)ch * STRIDE_N2,
                                   x_e2, xpart, N2c, 256,
                                   1, dst3b, 256);
        }
        hipLaunchKernelGGL((bn_apply_relu_kernel<256>), dim3(2048), dim3(256), 0, stream,
                           x_e2, N2c, dst3b, bn3b_g, bn3b_b);
    }
}

// Round 13
// 1857.435 us; speedup vs baseline: 1.1719x; 1.1719x over previous
//
#include <hip/hip_runtime.h>
#include <hip/hip_fp16.h>
#include <cstdint>
#include <algorithm>

// ---------------- problem constants ----------------
#define N1c 100000
#define N2c 80000
#define EPSc 1e-5f
#define STRIDE_N1 102400   // 100 blocks of 1024 (>= N1+1 bins)
#define STRIDE_N2 81920    // 80 blocks of 1024  (>= N2+1 bins)

typedef _Float16 fp16x8 __attribute__((ext_vector_type(8)));
typedef float f32x4 __attribute__((ext_vector_type(4)));

// ---------------- CSR build: one pass for ALL k-chunks of a layer ----------
__global__ __launch_bounds__(256) void rank2d_kernel(
    const int* __restrict__ out_idx, int* __restrict__ rank,
    int* __restrict__ bins, int E, int M, int q, int stride)
{
    for (int e = blockIdx.x * 256 + threadIdx.x; e < E; e += gridDim.x * 256) {
        int chunk = (e / M) / q;
        rank[e] = atomicAdd(&bins[chunk * stride + out_idx[e]], 1);
    }
}

__global__ __launch_bounds__(256) void scan1(
    const int* __restrict__ bins, int* __restrict__ ptr,
    int* __restrict__ bsums, int n)
{
    __shared__ int lds[256];
    int base = blockIdx.x * 1024;
    int v[4]; int t = 0;
    #pragma unroll
    for (int i = 0; i < 4; ++i) {
        int idx = base + threadIdx.x * 4 + i;
        v[i] = idx < n ? bins[idx] : 0;
        t += v[i];
    }
    lds[threadIdx.x] = t; __syncthreads();
    for (int off = 1; off < 256; off <<= 1) {
        int x = threadIdx.x >= off ? lds[threadIdx.x - off] : 0;
        __syncthreads();
        lds[threadIdx.x] += x;
        __syncthreads();
    }
    int run = lds[threadIdx.x] - t;
    if (threadIdx.x == 255) bsums[blockIdx.x] = lds[255];
    #pragma unroll
    for (int i = 0; i < 4; ++i) {
        int idx = base + threadIdx.x * 4 + i;
        if (idx < n) ptr[idx] = run;
        run += v[i];
    }
}

// serial exclusive scan of block sums, carry reset at chunk boundaries
__global__ __launch_bounds__(64) void scan2s(
    int* __restrict__ bsums, int bpc, int nch)
{
    int c = threadIdx.x;
    if (c < nch) {
        int run = 0;
        for (int i = 0; i < bpc; ++i) {
            int idx = c * bpc + i;
            int t = bsums[idx]; bsums[idx] = run; run += t;
        }
    }
}

__global__ __launch_bounds__(256) void scan3(
    int* __restrict__ ptr, const int* __restrict__ bsums, int n)
{
    int idx = blockIdx.x * 1024 + threadIdx.x * 4;
    int add = bsums[blockIdx.x];
    #pragma unroll
    for (int i = 0; i < 4; ++i)
        if (idx + i < n) ptr[idx + i] += add;
}

// ---------------- W pre-convert: Wh[k][c][j] = (fp16) W[k][j][c] ----------
__global__ __launch_bounds__(256) void wconv_fp16(
    const float* __restrict__ W, _Float16* __restrict__ Wh,
    int K, int CIN, int CTILE, int WST, int total)
{
    for (int idx = blockIdx.x * 256 + threadIdx.x; idx < total;
         idx += gridDim.x * 256) {
        int k = idx / (CTILE * CIN);
        int c = (idx / CIN) % CTILE;
        int j = idx % CIN;
        Wh[idx] = (_Float16)W[(size_t)k * CIN * WST + (size_t)j * WST + c];
    }
}

// ---------------- conv1a special: scatter (x_val, k) 8B per edge ----------
__global__ __launch_bounds__(256) void scatter_1a(
    const float* __restrict__ x, const int* __restrict__ iin,
    const int* __restrict__ iout, const int* __restrict__ ptr,
    const int* __restrict__ rank, float2* __restrict__ payload, int E, int M)
{
    for (int e = blockIdx.x * 256 + threadIdx.x; e < E; e += gridDim.x * 256) {
        int k = e / M;
        float2 p; p.x = x[iin[e]]; p.y = __int_as_float(k);
        payload[ptr[iout[e]] + rank[e]] = p;
    }
}

// out[o][c] = relu( sum_e val_e * W[k_e][c] ), W (125x32) in LDS, fp16 out
__global__ __launch_bounds__(256) void phaseB_1a(
    const float2* __restrict__ payload, const int* __restrict__ ptr,
    const float* __restrict__ W, __half* __restrict__ out, int n)
{
    __shared__ float Wl[125 * 32];
    for (int i = threadIdx.x; i < 125 * 32; i += 256) Wl[i] = W[i];
    __syncthreads();
    int total = n * 32;
    for (int idx = blockIdx.x * 256 + threadIdx.x; idx < total; idx += gridDim.x * 256) {
        int o = idx >> 5, c = idx & 31;
        int s0 = ptr[o], s1 = ptr[o + 1];
        float acc = 0.f;
        for (int s = s0; s < s1; ++s) {
            float2 p = payload[s];
            acc = fmaf(p.x, Wl[(__float_as_int(p.y) << 5) + c], acc);
        }
        out[idx] = __float2half(fmaxf(acc, 0.f));
    }
}

// ---------------- Phase A: MFMA gather-GEMM, PP=64, W in LDS -------------
// C[64 pairs][CTILE] = G[64][CIN] x Wt^T via mfma_f32_16x16x32_f16.
// r6-verified lane layout; r8-verified structure (Wt staged once per block
// from pre-converted fp16 Wh; r7's B-from-global caused an L2 storm).
// GMODE: 0 plain, 2 BN(scale/shift fp32)+ReLU at gather. Contrib fp16.
template <int CIN, int CTILE, int GMODE, int IN16>
__global__ __launch_bounds__(256, 3) void phaseA_mfma(
    const void* __restrict__ feats_, const _Float16* __restrict__ Wh,
    const int* __restrict__ in_idx, const int* __restrict__ out_idx,
    const int* __restrict__ ptr, const int* __restrict__ rank,
    __half* __restrict__ contrib, int M,
    const float* __restrict__ sc, const float* __restrict__ sh)
{
    constexpr int PP  = 64;              // pairs per block
    constexpr int NK  = CIN / 32;        // K-steps
    constexpr int NCF = CTILE / 16;      // col fragments
    constexpr int GCHK = CIN / 8;        // fp16x8 chunks per row
    constexpr int GSM  = (GCHK < 16 ? GCHK : 16) - 1;
    constexpr int RCH  = GCHK / 4;       // chunks per stager thread (>=1)
    static_assert(CIN % 32 == 0 && CTILE % 16 == 0 && RCH >= 1, "");

    __shared__ __align__(16) _Float16 Gl[PP * CIN];
    __shared__ __align__(16) _Float16 Wt[CTILE * CIN];
    __shared__ int sslot[PP];

    const int tid  = threadIdx.x;
    const int wave = tid >> 6;
    const int lane = tid & 63;
    const int k    = blockIdx.y;

    const int* iin  = in_idx  + (size_t)k * M;
    const int* iout = out_idx + (size_t)k * M;
    const int* rk   = rank    + (size_t)k * M;
    const _Float16* Wk = Wh + (size_t)k * CTILE * CIN;

    // ---- stage Wt ONCE per block (base-invariant), swizzled ----
    for (int i = tid; i < CTILE * GCHK; i += 256) {
        int row = i / GCHK, ch = i % GCHK;
        fp16x8 v = *(const fp16x8*)&Wk[(size_t)row * CIN + ch * 8];
        *(fp16x8*)&Wt[row * CIN + ((ch ^ (row & GSM)) << 3)] = v;
    }

    for (int base = blockIdx.x * PP; base < M; base += gridDim.x * PP) {
        if (tid < PP && base + tid < M)
            sslot[tid] = ptr[iout[base + tid]] + rk[base + tid];

        // ---- stage G: 4 threads per pair-row, swizzled 16B writes ----
        {
            int r = tid & 63;
            int h = tid >> 6;                // quarter of the row
            int p = base + r;
            if (p < M) {
                const int c0 = h * (CIN / 4);
                if (IN16) {
                    const _Float16* fr =
                        (const _Float16*)feats_ + (size_t)iin[p] * CIN + c0;
                    #pragma unroll
                    for (int cc = 0; cc < RCH; ++cc) {
                        int c = cc * 8;
                        fp16x8 v = *(const fp16x8*)(fr + c);
                        if (GMODE == 2) {
                            #pragma unroll
                            for (int j = 0; j < 8; ++j) {
                                float x = fmaf((float)v[j], sc[c0 + c + j],
                                               sh[c0 + c + j]);
                                v[j] = (_Float16)fmaxf(x, 0.f);
                            }
                        }
                        int ch = (c0 + c) >> 3;
                        *(fp16x8*)&Gl[r * CIN + ((ch ^ (r & GSM)) << 3)] = v;
                    }
                } else {
                    const float* fr =
                        (const float*)feats_ + (size_t)iin[p] * CIN + c0;
                    #pragma unroll
                    for (int cc = 0; cc < RCH; ++cc) {
                        int c = cc * 8;
                        float a[8];
                        *(float4*)&a[0] = *(const float4*)(fr + c);
                        *(float4*)&a[4] = *(const float4*)(fr + c + 4);
                        if (GMODE == 2) {
                            #pragma unroll
                            for (int j = 0; j < 8; ++j)
                                a[j] = fmaxf(fmaf(a[j], sc[c0 + c + j],
                                                  sh[c0 + c + j]), 0.f);
                        }
                        fp16x8 v;
                        #pragma unroll
                        for (int j = 0; j < 8; ++j) v[j] = (_Float16)a[j];
                        int ch = (c0 + c) >> 3;
                        *(fp16x8*)&Gl[r * CIN + ((ch ^ (r & GSM)) << 3)] = v;
                    }
                }
            }
        }
        __syncthreads();

        // ---- MFMA: wave owns 16 rows (wave*16), all CTILE cols ----
        f32x4 acc[NCF];
        #pragma unroll
        for (int cf = 0; cf < NCF; ++cf)
            acc[cf] = (f32x4){0.f, 0.f, 0.f, 0.f};

        const int lrow = lane & 15;
        const int lk8  = (lane >> 4) * 8;
        #pragma unroll
        for (int kk = 0; kk < NK; ++kk) {
            int col = kk * 32 + lk8;
            int r = wave * 16 + lrow;
            fp16x8 afr = *(const fp16x8*)
                &Gl[r * CIN + ((((col >> 3) ^ (r & GSM))) << 3)];
            #pragma unroll
            for (int cf = 0; cf < NCF; ++cf) {
                int rw = cf * 16 + lrow;
                fp16x8 bfr = *(const fp16x8*)
                    &Wt[rw * CIN + ((((col >> 3) ^ (rw & GSM))) << 3)];
                acc[cf] = __builtin_amdgcn_mfma_f32_16x16x32_f16(
                    afr, bfr, acc[cf], 0, 0, 0);
            }
        }

        // ---- epilogue: scatter rows via sslot, fp32->fp16 ----
        {
            int prb = wave * 16 + (lane >> 4) * 4;
            #pragma unroll
            for (int b = 0; b < 4; ++b) {
                int pr = prb + b;
                if (base + pr < M) {
                    size_t s = (size_t)sslot[pr];
                    #pragma unroll
                    for (int cf = 0; cf < NCF; ++cf)
                        contrib[s * CTILE + cf * 16 + lrow] =
                            __float2half(acc[cf][b]);
                }
            }
        }
        __syncthreads();
    }
}

// ---------------- Phase A for conv3b: dual cout-half, gather h3 ONCE -----
// Stages Gl (64x128 fp16) once per tile; loops half in {0,1} reloading only
// Wt (128x128, 32KB). Writes 256-wide contrib rows (r11-verified).
template <int GMODE>
__global__ __launch_bounds__(256, 3) void phaseA_mfma_3b(
    const void* __restrict__ feats_, const _Float16* __restrict__ Wh,
    const int* __restrict__ in_idx, const int* __restrict__ out_idx,
    const int* __restrict__ ptr, const int* __restrict__ rank,
    __half* __restrict__ contrib, int M,
    const float* __restrict__ sc, const float* __restrict__ sh)
{
    constexpr int CIN = 128, PP = 64, NK = 4, NCF = 8;
    constexpr int GCHK = 16, GSM = 15, RCH = 4;

    __shared__ __align__(16) _Float16 Gl[PP * CIN];     // 16KB
    __shared__ __align__(16) _Float16 Wt[128 * CIN];    // 32KB
    __shared__ int sslot[PP];

    const int tid  = threadIdx.x;
    const int wave = tid >> 6;
    const int lane = tid & 63;
    const int k    = blockIdx.y;

    const _Float16* feats = (const _Float16*)feats_;
    const int* iin  = in_idx  + (size_t)k * M;
    const int* iout = out_idx + (size_t)k * M;
    const int* rk   = rank    + (size_t)k * M;
    const _Float16* Wk = Wh + (size_t)k * 256 * CIN;    // [256 couts][128]

    const int lrow = lane & 15;
    const int lk8  = (lane >> 4) * 8;

    for (int base = blockIdx.x * PP; base < M; base += gridDim.x * PP) {
        if (tid < PP && base + tid < M)
            sslot[tid] = ptr[iout[base + tid]] + rk[base + tid];

        // ---- stage G once (IN16 + BN at gather) ----
        {
            int r = tid & 63;
            int h = tid >> 6;
            int p = base + r;
            if (p < M) {
                const int c0 = h * 32;
                const _Float16* fr = feats + (size_t)iin[p] * CIN + c0;
                #pragma unroll
                for (int cc = 0; cc < RCH; ++cc) {
                    int c = cc * 8;
                    fp16x8 v = *(const fp16x8*)(fr + c);
                    if (GMODE == 2) {
                        #pragma unroll
                        for (int j = 0; j < 8; ++j) {
                            float x = fmaf((float)v[j], sc[c0 + c + j],
                                           sh[c0 + c + j]);
                            v[j] = (_Float16)fmaxf(x, 0.f);
                        }
                    }
                    int ch = (c0 + c) >> 3;
                    *(fp16x8*)&Gl[r * CIN + ((ch ^ (r & GSM)) << 3)] = v;
                }
            }
        }

        #pragma unroll
        for (int half = 0; half < 2; ++half) {
            __syncthreads();   // Gl ready / previous half's MFMA done with Wt
            // stage Wt for this half (rows half*128 .. half*128+127)
            for (int i = tid; i < 128 * GCHK; i += 256) {
                int row = i / GCHK, ch = i % GCHK;
                fp16x8 v = *(const fp16x8*)
                    &Wk[(size_t)(half * 128 + row) * CIN + ch * 8];
                *(fp16x8*)&Wt[row * CIN + ((ch ^ (row & GSM)) << 3)] = v;
            }
            __syncthreads();

            f32x4 acc[NCF];
            #pragma unroll
            for (int cf = 0; cf < NCF; ++cf)
                acc[cf] = (f32x4){0.f, 0.f, 0.f, 0.f};

            #pragma unroll
            for (int kk = 0; kk < NK; ++kk) {
                int col = kk * 32 + lk8;
                int r = wave * 16 + lrow;
                fp16x8 afr = *(const fp16x8*)
                    &Gl[r * CIN + ((((col >> 3) ^ (r & GSM))) << 3)];
                #pragma unroll
                for (int cf = 0; cf < NCF; ++cf) {
                    int rw = cf * 16 + lrow;
                    fp16x8 bfr = *(const fp16x8*)
                        &Wt[rw * CIN + ((((col >> 3) ^ (rw & GSM))) << 3)];
                    acc[cf] = __builtin_amdgcn_mfma_f32_16x16x32_f16(
                        afr, bfr, acc[cf], 0, 0, 0);
                }
            }

            // epilogue: scatter 256-wide rows via sslot
            int prb = wave * 16 + (lane >> 4) * 4;
            #pragma unroll
            for (int b = 0; b < 4; ++b) {
                int pr = prb + b;
                if (base + pr < M) {
                    size_t s = (size_t)sslot[pr];
                    #pragma unroll
                    for (int cf = 0; cf < NCF; ++cf)
                        contrib[s * 256 + half * 128 + cf * 16 + lrow] =
                            __float2half(acc[cf][b]);
                }
            }
        }
        __syncthreads();
    }
}

// ---------------- Phase B: scalar segmented sum (one channel/thread) -----
// r12 lesson: V=4 vectorization HURT (190->240us/dispatch) — fewer work
// items + longer per-item chains = less memory-level parallelism for this
// latency-bound segmented reduce. Scalar V=1 (r11-verified at 1.2TB/s) it is.
// OUT16=1: fp16 out (intermediates / partial buffers); 0: fp32 out.
// PARTIN=1: accum source is the tight fp16 partial part_in[o*CSTR+c].
template <int CSTR, bool STATS, int OUT16, int PARTIN>
__global__ __launch_bounds__(256) void phaseB8(
    const __half* __restrict__ contrib, const int* __restrict__ ptr,
    void* __restrict__ out_, const __half* __restrict__ part_in,
    int n, int ostr, int accum,
    double* __restrict__ statsbuf, int sqoff)
{
    float s1 = 0.f, s2 = 0.f;
    int total = n * CSTR;
    for (int idx = blockIdx.x * 256 + threadIdx.x; idx < total;
         idx += gridDim.x * 256) {
        int o = idx / CSTR, c = idx % CSTR;
        int a = ptr[o], b = ptr[o + 1];
        size_t oi = (size_t)o * ostr + c;
        float acc;
        if (accum) {
            if (PARTIN)
                acc = __half2float(part_in[(size_t)o * CSTR + c]);
            else if (OUT16)
                acc = __half2float(((const __half*)out_)[oi]);
            else
                acc = ((const float*)out_)[oi];
        } else {
            acc = 0.f;
        }
        for (int s = a; s < b; ++s)
            acc += __half2float(contrib[(size_t)s * CSTR + c]);
        if (OUT16) ((__half*)out_)[oi] = __float2half(acc);
        else       ((float*)out_)[oi] = acc;
        if (STATS) { s1 += acc; s2 += acc * acc; }
    }
    if constexpr (STATS) {
        __shared__ double l1[256], l2[256];
        l1[threadIdx.x] = (double)s1; l2[threadIdx.x] = (double)s2;
        __syncthreads();
        for (int off = 128; off >= CSTR; off >>= 1) {
            if (threadIdx.x < (unsigned)off) {
                l1[threadIdx.x] += l1[threadIdx.x + off];
                l2[threadIdx.x] += l2[threadIdx.x + off];
            }
            __syncthreads();
        }
        if (threadIdx.x < CSTR) {
            atomicAdd(&statsbuf[threadIdx.x], l1[threadIdx.x]);
            atomicAdd(&statsbuf[sqoff + threadIdx.x], l2[threadIdx.x]);
        }
    }
}

// ---------------- BN helpers (fp64 stats) ----------------
template <int C>
__global__ __launch_bounds__(256) void make_scsh(
    const double* __restrict__ sums, const float* __restrict__ g,
    const float* __restrict__ b, float* __restrict__ sc, float* __restrict__ sh,
    double inv_n)
{
    int c = threadIdx.x;
    if (c < C) {
        double mean = sums[c] * inv_n;
        double var  = sums[C + c] * inv_n - mean * mean;
        float s = g[c] * (float)(1.0 / sqrt(var + (double)EPSc));
        sc[c] = s;
        sh[c] = b[c] - (float)mean * s;
    }
}

template <int C>
__global__ __launch_bounds__(256) void bn_apply_relu_kernel(
    float* __restrict__ x, int n, const double* __restrict__ sums,
    const float* __restrict__ g, const float* __restrict__ b)
{
    const int c = threadIdx.x % C;
    const double inv_n = 1.0 / (double)n;
    double mean = sums[c] * inv_n;
    double var  = sums[C + c] * inv_n - mean * mean;
    float scale = g[c] * (float)(1.0 / sqrt(var + (double)EPSc));
    float shift = b[c] - (float)mean * scale;
    size_t total = (size_t)n * C;
    size_t stride = (size_t)gridDim.x * 256;
    for (size_t i = (size_t)blockIdx.x * 256 + threadIdx.x; i < total; i += stride)
        x[i] = fmaxf(x[i] * scale + shift, 0.f);
}

// Variant that also writes an fp16 shadow copy (for the next layer's gather).
template <int C>
__global__ __launch_bounds__(256) void bn_apply_relu_shadow_kernel(
    float* __restrict__ x, __half* __restrict__ xh, int n,
    const double* __restrict__ sums,
    const float* __restrict__ g, const float* __restrict__ b)
{
    const int c = threadIdx.x % C;
    const double inv_n = 1.0 / (double)n;
    double mean = sums[c] * inv_n;
    double var  = sums[C + c] * inv_n - mean * mean;
    float scale = g[c] * (float)(1.0 / sqrt(var + (double)EPSc));
    float shift = b[c] - (float)mean * scale;
    size_t total = (size_t)n * C;
    size_t stride = (size_t)gridDim.x * 256;
    for (size_t i = (size_t)blockIdx.x * 256 + threadIdx.x; i < total; i += stride) {
        float v = fmaxf(x[i] * scale + shift, 0.f);
        x[i] = v;
        xh[i] = __float2half(v);
    }
}

// ---------------- host-side helpers ----------------
struct Plan { int q, nch; };

static Plan make_plan(long long tot_elems, int K, long long cap, int maxch)
{
    if (cap < 1) cap = 1;
    long long nch0 = (tot_elems + cap - 1) / cap;
    if (nch0 < 1) nch0 = 1;
    if (nch0 > K) nch0 = K;
    int q = (int)((K + nch0 - 1) / nch0);
    int nch = (K + q - 1) / q;
    if (nch > maxch) { q = (K + maxch - 1) / maxch; nch = (K + q - 1) / q; }
    return { q, nch };
}

static void build_csr2d(const int* iout, int* rank, int* bins, int* ptr, int* bsums,
                        int E, int M, int q, int nch, int stride, hipStream_t s)
{
    hipMemsetAsync(bins, 0, (size_t)nch * stride * sizeof(int), s);
    int gb = std::min(2048, (E + 255) / 256);
    hipLaunchKernelGGL(rank2d_kernel, dim3(gb), dim3(256), 0, s, iout, rank, bins, E, M, q, stride);
    int totalbins = nch * stride, nb = totalbins / 1024, bpc = stride / 1024;
    hipLaunchKernelGGL(scan1, dim3(nb), dim3(256), 0, s, bins, ptr, bsums, totalbins);
    hipLaunchKernelGGL(scan2s, dim3(1), dim3(64), 0, s, bsums, bpc, nch);
    hipLaunchKernelGGL(scan3, dim3(nb), dim3(256), 0, s, ptr, bsums, totalbins);
}

// One full layer (no cout split): k-chunked as needed.
template <int CIN, int COUT, int GMODE, bool STATS, int IN16, int OUT16>
static void run_layer(const void* feats, const float* W,
                      const int* iin, const int* iout, void* outp,
                      int M, int K, int n_out, int stride, int maxch,
                      int* bins, int* ptr, int* bsums, int* rank, __half* contrib,
                      _Float16* wh, long long cap_f32,
                      const float* sc, const float* sh,
                      double* statsbuf, hipStream_t s)
{
    int wtot = K * COUT * CIN;
    hipLaunchKernelGGL(wconv_fp16, dim3(std::min(2048, (wtot + 255) / 256)),
                       dim3(256), 0, s, W, wh, K, CIN, COUT, COUT, wtot);
    long long cap_h = cap_f32 * 2;
    Plan pl = make_plan((long long)K * M * COUT, K, cap_h, maxch);
    build_csr2d(iout, rank, bins, ptr, bsums, K * M, M, pl.q, pl.nch, stride, s);
    for (int ch = 0; ch < pl.nch; ++ch) {
        int k0 = ch * pl.q;
        int qc = std::min(pl.q, K - k0);
        dim3 g((M + 63) / 64, qc);
        hipLaunchKernelGGL((phaseA_mfma<CIN, COUT, GMODE, IN16>), g, dim3(256), 0, s,
                           feats, wh + (size_t)k0 * COUT * CIN,
                           iin + (size_t)k0 * M, iout + (size_t)k0 * M,
                           ptr + (size_t)ch * stride, rank + (size_t)k0 * M,
                           contrib, M, sc, sh);
        bool last = (ch == pl.nch - 1);
        if (STATS && last)
            hipLaunchKernelGGL((phaseB8<COUT, true, OUT16, 0>), dim3(2048), dim3(256), 0, s,
                               contrib, ptr + (size_t)ch * stride, outp,
                               (const __half*)nullptr, n_out, COUT,
                               ch ? 1 : 0, statsbuf, COUT);
        else
            hipLaunchKernelGGL((phaseB8<COUT, false, OUT16, 0>), dim3(2048), dim3(256), 0, s,
                               contrib, ptr + (size_t)ch * stride, outp,
                               (const __half*)nullptr, n_out, COUT,
                               ch ? 1 : 0, (double*)nullptr, 0);
    }
}

extern "C" void kernel_launch(void* const* d_in, const int* in_sizes, int n_in,
                              void* d_out, int out_size, void* d_ws, size_t ws_size,
                              hipStream_t stream)
{
    const float* x_feats = (const float*)d_in[0];
    const float* w1a = (const float*)d_in[1];
    const float* w1b = (const float*)d_in[2];
    const float* w1c = (const float*)d_in[3];
    const float* w2  = (const float*)d_in[4];
    const float* w3a = (const float*)d_in[5];
    const float* w3b = (const float*)d_in[6];
    const float* bn1b_g = (const float*)d_in[7];
    const float* bn1b_b = (const float*)d_in[8];
    const float* bn1c_g = (const float*)d_in[9];
    const float* bn1c_b = (const float*)d_in[10];
    const float* bn3a_g = (const float*)d_in[11];
    const float* bn3a_b = (const float*)d_in[12];
    const float* bn3b_g = (const float*)d_in[13];
    const float* bn3b_b = (const float*)d_in[14];
    const int* km1a_in  = (const int*)d_in[15];
    const int* km1a_out = (const int*)d_in[16];
    const int* km1b_in  = (const int*)d_in[17];
    const int* km1b_out = (const int*)d_in[18];
    const int* km1c_in  = (const int*)d_in[19];
    const int* km1c_out = (const int*)d_in[20];
    const int* km2_in   = (const int*)d_in[21];
    const int* km2_out  = (const int*)d_in[22];
    const int* km3a_in  = (const int*)d_in[23];
    const int* km3a_out = (const int*)d_in[24];
    const int* km3b_in  = (const int*)d_in[25];
    const int* km3b_out = (const int*)d_in[26];

    float* out  = (float*)d_out;
    float* x_e1 = out;                       // [N1,32] fp32 (final)
    float* x_e2 = out + (size_t)N1c * 32;    // [N2,256] fp32 (final)

    // ---- workspace layout (float-element offsets, 16B-aligned) ----
    float* ws = (float*)d_ws;
    float*  poolA  = ws;                        // 10,240,000 (h1 -> h3, fp16)
    float*  poolB  = poolA + 10240000;          //  5,120,000 (h2 -> h2b+xe1h)
    double* dstats = (double*)(poolB + 5120000);//  2,048 doubles
    float*  scsh   = (float*)(dstats + 2048);   //  1,024
    int*    bins   = (int*)(scsh + 1024);       //  819,200
    int*    ptr    = bins + 819200;             //  819,200
    int*    bsums  = ptr + 819200;              //  1,024
    int*    rank   = bsums + 1024;              //  2,500,000
    float*  whf    = (float*)(rank + 2500000);  //  442,400 (fp16 W^T buffer)
    _Float16* wh   = (_Float16*)whf;
    float*  contribf = whf + 442400;
    __half* contrib  = (__half*)contribf;
    const long long FIXED = 10240000LL + 5120000 + 4096 + 1024
                          + 819200 + 819200 + 1024 + 2500000 + 442400;
    long long cap = (long long)(ws_size / 4) - FIXED - 32;   // fp32 elems left
    if (cap < 1) cap = 1;

    __half* h1  = (__half*)poolA;   // [N1,32] fp16
    __half* h3  = (__half*)poolA;   // [N2,128] fp16 = poolA floats [0,5.12M)
    __half* h2  = (__half*)poolB;   // [N1,32] fp16
    __half* h2b = (__half*)poolB;   // [N2,64] fp16 (h2 dead by then)
    __half* xe1h = (__half*)poolB + 5120000;  // [N1,32] fp16 shadow of x_e1
    // conv3b partial buffer: 80000*256 fp16 = 20.48M halfs = 10.24M floats,
    // overlaid on poolA floats [5.12M,10.24M) + all of poolB — all dead by
    // conv3b (h1/h2/h2b/xe1h consumed; h3 occupies only poolA [0,5.12M)).
    __half* xpart = (__half*)(poolA + 5120000);

    double* dst1b = dstats;
    double* dst1c = dstats + 512;
    double* dst3a = dstats + 1024;
    double* dst3b = dstats + 1536;
    float* sc1b = scsh,       *sh1b = scsh + 32;
    float* sc3a = scsh + 256, *sh3a = scsh + 384;

    hipMemsetAsync(dstats, 0, 2048 * sizeof(double), stream);

    // ---- conv1a (1->32, K=125) + ReLU: scatter (val,k) + W-in-LDS reduce ----
    {
        build_csr2d(km1a_out, rank, bins, ptr, bsums, 125 * 20000, 20000, 125, 1,
                    STRIDE_N1, stream);
        hipLaunchKernelGGL(scatter_1a, dim3(2048), dim3(256), 0, stream,
                           x_feats, km1a_in, km1a_out, ptr, rank, (float2*)contribf,
                           125 * 20000, 20000);
        hipLaunchKernelGGL(phaseB_1a, dim3(2048), dim3(256), 0, stream,
                           (const float2*)contribf, ptr, w1a, h1, N1c);
    }

    // ---- conv1b (32->32, K=125): fp16 in/out + fp64 stats; BN fused later ----
    run_layer<32, 32, 0, true, 1, 1>(h1, w1b, km1b_in, km1b_out, h2, 20000, 125, N1c,
                                     STRIDE_N1, 8, bins, ptr, bsums, rank, contrib,
                                     wh, cap, nullptr, nullptr, dst1b, stream);
    hipLaunchKernelGGL((make_scsh<32>), dim3(1), dim3(256), 0, stream,
                       dst1b, bn1b_g, bn1b_b, sc1b, sh1b, 1.0 / N1c);

    // ---- conv1c (32->32, K=125): BN(h2)+ReLU at gather; x_e1 fp32 + stats ----
    run_layer<32, 32, 2, true, 1, 0>(h2, w1c, km1c_in, km1c_out, x_e1, 20000, 125, N1c,
                                     STRIDE_N1, 8, bins, ptr, bsums, rank, contrib,
                                     wh, cap, sc1b, sh1b, dst1c, stream);
    // BN+ReLU on x_e1 (final fp32) + fp16 shadow for conv2's gather
    hipLaunchKernelGGL((bn_apply_relu_shadow_kernel<32>), dim3(2048), dim3(256), 0, stream,
                       x_e1, xe1h, N1c, dst1c, bn1c_g, bn1c_b);

    // ---- conv2 (32->64, K=27): fp16 in (xe1h), fp16 out, no activation ----
    run_layer<32, 64, 0, false, 1, 1>(xe1h, w2, km2_in, km2_out, h2b, 30000, 27, N2c,
                                      STRIDE_N2, 10, bins, ptr, bsums, rank, contrib,
                                      wh, cap, nullptr, nullptr, nullptr, stream);

    // ---- conv3a (64->128, K=27): fp16 in/out + stats; BN fused at conv3b ----
    run_layer<64, 128, 0, true, 1, 1>(h2b, w3a, km3a_in, km3a_out, h3, 20000, 27, N2c,
                                      STRIDE_N2, 10, bins, ptr, bsums, rank, contrib,
                                      wh, cap, nullptr, nullptr, dst3a, stream);
    hipLaunchKernelGGL((make_scsh<128>), dim3(1), dim3(256), 0, stream,
                       dst3a, bn3a_g, bn3a_b, sc3a, sh3a, 1.0 / N2c);

    // ---- conv3b (128->256, K=27): dual-half phaseA (gather h3 once) ----
    // Multi-chunk phaseB accumulates through a fp16 partial (xpart): non-last
    // passes write fp16 (halves the wasted HBM writes of the fp32 accum);
    // the last pass reads the partial (L3-hot) and writes final fp32 + stats.
    {
        const int M = 20000, K = 27;
        int wtot = K * 256 * 128;
        hipLaunchKernelGGL(wconv_fp16, dim3(2048), dim3(256), 0, stream,
                           w3b, wh, K, 128, 256, 256, wtot);
        Plan pl = make_plan((long long)K * M * 256, K, cap * 2, 10);
        build_csr2d(km3b_out, rank, bins, ptr, bsums, K * M, M, pl.q, pl.nch,
                    STRIDE_N2, stream);
        for (int ch = 0; ch < pl.nch; ++ch) {
            int k0 = ch * pl.q;
            int qc = std::min(pl.q, K - k0);
            dim3 g((M + 63) / 64, qc);
            hipLaunchKernelGGL((phaseA_mfma_3b<2>), g, dim3(256), 0, stream,
                               (const void*)h3, wh + (size_t)k0 * 256 * 128,
                               km3b_in + (size_t)k0 * M, km3b_out + (size_t)k0 * M,
                               ptr + (size_t)ch * STRIDE_N2, rank + (size_t)k0 * M,
                               contrib, M, sc3a, sh3a);
            bool last = (ch == pl.nch - 1);
            if (!last)
                // partial pass: fp16 out to xpart (accum from xpart if ch>0)
                hipLaunchKernelGGL((phaseB8<256, false, 1, 0>), dim3(2048), dim3(256), 0, stream,
                                   contrib, ptr + (size_t)ch * STRIDE_N2,
                                   xpart, (const __half*)nullptr, N2c, 256,
                                   ch ? 1 : 0, (double*)nullptr, 0);
            else if (ch == 0)
                // single-chunk case: direct fp32 + stats
                hipLaunchKernelGGL((phaseB8<256, true, 0, 0>), dim3(2048), dim3(256), 0, stream,
                                   contrib, ptr + (size_t)ch * STRIDE_N2,
                                   x_e2, (const __half*)nullptr, N2c, 256,
                                   0, dst3b, 256);
            else
                // final pass: accum from fp16 partial, write fp32 + stats
                hipLaunchKernelGGL((phaseB8<256, true, 0, 1>), dim3(2048), dim3(256), 0, stream,
                                   contrib, ptr + (size_t)ch * STRIDE_N2,
                                   x_e2, xpart, N2c, 256,
                                   1, dst3b, 256);
        }
        hipLaunchKernelGGL((bn_apply_relu_kernel<256>), dim3(2048), dim3(256), 0, stream,
                           x_e2, N2c, dst3b, bn3b_g, bn3b_b);
    }
}

// Round 14
// 1789.143 us; speedup vs baseline: 1.2166x; 1.0382x over previous
//
#include <hip/hip_runtime.h>
#include <hip/hip_fp16.h>
#include <cstdint>
#include <algorithm>

// ---------------- problem constants ----------------
#define N1c 100000
#define N2c 80000
#define EPSc 1e-5f
#define STRIDE_N1 102400   // 100 blocks of 1024 (>= N1+1 bins)
#define STRIDE_N2 81920    // 80 blocks of 1024  (>= N2+1 bins)

typedef _Float16 fp16x8 __attribute__((ext_vector_type(8)));
typedef float f32x4 __attribute__((ext_vector_type(4)));

// ---------------- CSR build: one pass for ALL k-chunks of a layer ----------
__global__ __launch_bounds__(256) void rank2d_kernel(
    const int* __restrict__ out_idx, int* __restrict__ rank,
    int* __restrict__ bins, int E, int M, int q, int stride)
{
    for (int e = blockIdx.x * 256 + threadIdx.x; e < E; e += gridDim.x * 256) {
        int chunk = (e / M) / q;
        rank[e] = atomicAdd(&bins[chunk * stride + out_idx[e]], 1);
    }
}

__global__ __launch_bounds__(256) void scan1(
    const int* __restrict__ bins, int* __restrict__ ptr,
    int* __restrict__ bsums, int n)
{
    __shared__ int lds[256];
    int base = blockIdx.x * 1024;
    int v[4]; int t = 0;
    #pragma unroll
    for (int i = 0; i < 4; ++i) {
        int idx = base + threadIdx.x * 4 + i;
        v[i] = idx < n ? bins[idx] : 0;
        t += v[i];
    }
    lds[threadIdx.x] = t; __syncthreads();
    for (int off = 1; off < 256; off <<= 1) {
        int x = threadIdx.x >= off ? lds[threadIdx.x - off] : 0;
        __syncthreads();
        lds[threadIdx.x] += x;
        __syncthreads();
    }
    int run = lds[threadIdx.x] - t;
    if (threadIdx.x == 255) bsums[blockIdx.x] = lds[255];
    #pragma unroll
    for (int i = 0; i < 4; ++i) {
        int idx = base + threadIdx.x * 4 + i;
        if (idx < n) ptr[idx] = run;
        run += v[i];
    }
}

// serial exclusive scan of block sums, carry reset at chunk boundaries
__global__ __launch_bounds__(64) void scan2s(
    int* __restrict__ bsums, int bpc, int nch)
{
    int c = threadIdx.x;
    if (c < nch) {
        int run = 0;
        for (int i = 0; i < bpc; ++i) {
            int idx = c * bpc + i;
            int t = bsums[idx]; bsums[idx] = run; run += t;
        }
    }
}

__global__ __launch_bounds__(256) void scan3(
    int* __restrict__ ptr, const int* __restrict__ bsums, int n)
{
    int idx = blockIdx.x * 1024 + threadIdx.x * 4;
    int add = bsums[blockIdx.x];
    #pragma unroll
    for (int i = 0; i < 4; ++i)
        if (idx + i < n) ptr[idx + i] += add;
}

// ---------------- W pre-convert: Wh[k][c][j] = (fp16) W[k][j][c] ----------
__global__ __launch_bounds__(256) void wconv_fp16(
    const float* __restrict__ W, _Float16* __restrict__ Wh,
    int K, int CIN, int CTILE, int WST, int total)
{
    for (int idx = blockIdx.x * 256 + threadIdx.x; idx < total;
         idx += gridDim.x * 256) {
        int k = idx / (CTILE * CIN);
        int c = (idx / CIN) % CTILE;
        int j = idx % CIN;
        Wh[idx] = (_Float16)W[(size_t)k * CIN * WST + (size_t)j * WST + c];
    }
}

// ---------------- conv1a special: scatter (x_val, k) 8B per edge ----------
__global__ __launch_bounds__(256) void scatter_1a(
    const float* __restrict__ x, const int* __restrict__ iin,
    const int* __restrict__ iout, const int* __restrict__ ptr,
    const int* __restrict__ rank, float2* __restrict__ payload, int E, int M)
{
    for (int e = blockIdx.x * 256 + threadIdx.x; e < E; e += gridDim.x * 256) {
        int k = e / M;
        float2 p; p.x = x[iin[e]]; p.y = __int_as_float(k);
        payload[ptr[iout[e]] + rank[e]] = p;
    }
}

// out[o][c] = relu( sum_e val_e * W[k_e][c] ), W (125x32) in LDS, fp16 out.
// Slot loop batched 4-deep (independent loads -> 4x MLP vs serial chain).
__global__ __launch_bounds__(256) void phaseB_1a(
    const float2* __restrict__ payload, const int* __restrict__ ptr,
    const float* __restrict__ W, __half* __restrict__ out, int n)
{
    __shared__ float Wl[125 * 32];
    for (int i = threadIdx.x; i < 125 * 32; i += 256) Wl[i] = W[i];
    __syncthreads();
    int total = n * 32;
    for (int idx = blockIdx.x * 256 + threadIdx.x; idx < total; idx += gridDim.x * 256) {
        int o = idx >> 5, c = idx & 31;
        int s0 = ptr[o], s1 = ptr[o + 1];
        float acc = 0.f;
        for (int s = s0; s < s1; s += 4) {
            float2 p0 = payload[s];
            float2 p1 = (s + 1 < s1) ? payload[s + 1] : make_float2(0.f, 0.f);
            float2 p2 = (s + 2 < s1) ? payload[s + 2] : make_float2(0.f, 0.f);
            float2 p3 = (s + 3 < s1) ? payload[s + 3] : make_float2(0.f, 0.f);
            float t0 = fmaf(p0.x, Wl[(__float_as_int(p0.y) << 5) + c], 0.f);
            float t1 = (s + 1 < s1)
                ? p1.x * Wl[(__float_as_int(p1.y) << 5) + c] : 0.f;
            float t2 = (s + 2 < s1)
                ? p2.x * Wl[(__float_as_int(p2.y) << 5) + c] : 0.f;
            float t3 = (s + 3 < s1)
                ? p3.x * Wl[(__float_as_int(p3.y) << 5) + c] : 0.f;
            acc += ((t0 + t1) + (t2 + t3));
        }
        out[idx] = __float2half(fmaxf(acc, 0.f));
    }
}

// ---------------- Phase A: MFMA gather-GEMM, PP=64, W in LDS -------------
// C[64 pairs][CTILE] = G[64][CIN] x Wt^T via mfma_f32_16x16x32_f16.
// r6-verified lane layout; r8-verified structure (Wt staged once per block
// from pre-converted fp16 Wh; r7's B-from-global caused an L2 storm).
// GMODE: 0 plain, 2 BN(scale/shift fp32)+ReLU at gather. Contrib fp16.
template <int CIN, int CTILE, int GMODE, int IN16>
__global__ __launch_bounds__(256, 3) void phaseA_mfma(
    const void* __restrict__ feats_, const _Float16* __restrict__ Wh,
    const int* __restrict__ in_idx, const int* __restrict__ out_idx,
    const int* __restrict__ ptr, const int* __restrict__ rank,
    __half* __restrict__ contrib, int M,
    const float* __restrict__ sc, const float* __restrict__ sh)
{
    constexpr int PP  = 64;              // pairs per block
    constexpr int NK  = CIN / 32;        // K-steps
    constexpr int NCF = CTILE / 16;      // col fragments
    constexpr int GCHK = CIN / 8;        // fp16x8 chunks per row
    constexpr int GSM  = (GCHK < 16 ? GCHK : 16) - 1;
    constexpr int RCH  = GCHK / 4;       // chunks per stager thread (>=1)
    static_assert(CIN % 32 == 0 && CTILE % 16 == 0 && RCH >= 1, "");

    __shared__ __align__(16) _Float16 Gl[PP * CIN];
    __shared__ __align__(16) _Float16 Wt[CTILE * CIN];
    __shared__ int sslot[PP];

    const int tid  = threadIdx.x;
    const int wave = tid >> 6;
    const int lane = tid & 63;
    const int k    = blockIdx.y;

    const int* iin  = in_idx  + (size_t)k * M;
    const int* iout = out_idx + (size_t)k * M;
    const int* rk   = rank    + (size_t)k * M;
    const _Float16* Wk = Wh + (size_t)k * CTILE * CIN;

    // ---- stage Wt ONCE per block (base-invariant), swizzled ----
    for (int i = tid; i < CTILE * GCHK; i += 256) {
        int row = i / GCHK, ch = i % GCHK;
        fp16x8 v = *(const fp16x8*)&Wk[(size_t)row * CIN + ch * 8];
        *(fp16x8*)&Wt[row * CIN + ((ch ^ (row & GSM)) << 3)] = v;
    }

    for (int base = blockIdx.x * PP; base < M; base += gridDim.x * PP) {
        if (tid < PP && base + tid < M)
            sslot[tid] = ptr[iout[base + tid]] + rk[base + tid];

        // ---- stage G: 4 threads per pair-row, swizzled 16B writes ----
        {
            int r = tid & 63;
            int h = tid >> 6;                // quarter of the row
            int p = base + r;
            if (p < M) {
                const int c0 = h * (CIN / 4);
                if (IN16) {
                    const _Float16* fr =
                        (const _Float16*)feats_ + (size_t)iin[p] * CIN + c0;
                    #pragma unroll
                    for (int cc = 0; cc < RCH; ++cc) {
                        int c = cc * 8;
                        fp16x8 v = *(const fp16x8*)(fr + c);
                        if (GMODE == 2) {
                            #pragma unroll
                            for (int j = 0; j < 8; ++j) {
                                float x = fmaf((float)v[j], sc[c0 + c + j],
                                               sh[c0 + c + j]);
                                v[j] = (_Float16)fmaxf(x, 0.f);
                            }
                        }
                        int ch = (c0 + c) >> 3;
                        *(fp16x8*)&Gl[r * CIN + ((ch ^ (r & GSM)) << 3)] = v;
                    }
                } else {
                    const float* fr =
                        (const float*)feats_ + (size_t)iin[p] * CIN + c0;
                    #pragma unroll
                    for (int cc = 0; cc < RCH; ++cc) {
                        int c = cc * 8;
                        float a[8];
                        *(float4*)&a[0] = *(const float4*)(fr + c);
                        *(float4*)&a[4] = *(const float4*)(fr + c + 4);
                        if (GMODE == 2) {
                            #pragma unroll
                            for (int j = 0; j < 8; ++j)
                                a[j] = fmaxf(fmaf(a[j], sc[c0 + c + j],
                                                  sh[c0 + c + j]), 0.f);
                        }
                        fp16x8 v;
                        #pragma unroll
                        for (int j = 0; j < 8; ++j) v[j] = (_Float16)a[j];
                        int ch = (c0 + c) >> 3;
                        *(fp16x8*)&Gl[r * CIN + ((ch ^ (r & GSM)) << 3)] = v;
                    }
                }
            }
        }
        __syncthreads();

        // ---- MFMA: wave owns 16 rows (wave*16), all CTILE cols ----
        f32x4 acc[NCF];
        #pragma unroll
        for (int cf = 0; cf < NCF; ++cf)
            acc[cf] = (f32x4){0.f, 0.f, 0.f, 0.f};

        const int lrow = lane & 15;
        const int lk8  = (lane >> 4) * 8;
        #pragma unroll
        for (int kk = 0; kk < NK; ++kk) {
            int col = kk * 32 + lk8;
            int r = wave * 16 + lrow;
            fp16x8 afr = *(const fp16x8*)
                &Gl[r * CIN + ((((col >> 3) ^ (r & GSM))) << 3)];
            #pragma unroll
            for (int cf = 0; cf < NCF; ++cf) {
                int rw = cf * 16 + lrow;
                fp16x8 bfr = *(const fp16x8*)
                    &Wt[rw * CIN + ((((col >> 3) ^ (rw & GSM))) << 3)];
                acc[cf] = __builtin_amdgcn_mfma_f32_16x16x32_f16(
                    afr, bfr, acc[cf], 0, 0, 0);
            }
        }

        // ---- epilogue: scatter rows via sslot, fp32->fp16 ----
        {
            int prb = wave * 16 + (lane >> 4) * 4;
            #pragma unroll
            for (int b = 0; b < 4; ++b) {
                int pr = prb + b;
                if (base + pr < M) {
                    size_t s = (size_t)sslot[pr];
                    #pragma unroll
                    for (int cf = 0; cf < NCF; ++cf)
                        contrib[s * CTILE + cf * 16 + lrow] =
                            __float2half(acc[cf][b]);
                }
            }
        }
        __syncthreads();
    }
}

// ---------------- Phase A for conv3b: dual cout-half, gather h3 ONCE -----
// Stages Gl (64x128 fp16) once per tile; loops half in {0,1} reloading only
// Wt (128x128, 32KB). Writes 256-wide contrib rows (r11-verified).
template <int GMODE>
__global__ __launch_bounds__(256, 3) void phaseA_mfma_3b(
    const void* __restrict__ feats_, const _Float16* __restrict__ Wh,
    const int* __restrict__ in_idx, const int* __restrict__ out_idx,
    const int* __restrict__ ptr, const int* __restrict__ rank,
    __half* __restrict__ contrib, int M,
    const float* __restrict__ sc, const float* __restrict__ sh)
{
    constexpr int CIN = 128, PP = 64, NK = 4, NCF = 8;
    constexpr int GCHK = 16, GSM = 15, RCH = 4;

    __shared__ __align__(16) _Float16 Gl[PP * CIN];     // 16KB
    __shared__ __align__(16) _Float16 Wt[128 * CIN];    // 32KB
    __shared__ int sslot[PP];

    const int tid  = threadIdx.x;
    const int wave = tid >> 6;
    const int lane = tid & 63;
    const int k    = blockIdx.y;

    const _Float16* feats = (const _Float16*)feats_;
    const int* iin  = in_idx  + (size_t)k * M;
    const int* iout = out_idx + (size_t)k * M;
    const int* rk   = rank    + (size_t)k * M;
    const _Float16* Wk = Wh + (size_t)k * 256 * CIN;    // [256 couts][128]

    const int lrow = lane & 15;
    const int lk8  = (lane >> 4) * 8;

    for (int base = blockIdx.x * PP; base < M; base += gridDim.x * PP) {
        if (tid < PP && base + tid < M)
            sslot[tid] = ptr[iout[base + tid]] + rk[base + tid];

        // ---- stage G once (IN16 + BN at gather) ----
        {
            int r = tid & 63;
            int h = tid >> 6;
            int p = base + r;
            if (p < M) {
                const int c0 = h * 32;
                const _Float16* fr = feats + (size_t)iin[p] * CIN + c0;
                #pragma unroll
                for (int cc = 0; cc < RCH; ++cc) {
                    int c = cc * 8;
                    fp16x8 v = *(const fp16x8*)(fr + c);
                    if (GMODE == 2) {
                        #pragma unroll
                        for (int j = 0; j < 8; ++j) {
                            float x = fmaf((float)v[j], sc[c0 + c + j],
                                           sh[c0 + c + j]);
                            v[j] = (_Float16)fmaxf(x, 0.f);
                        }
                    }
                    int ch = (c0 + c) >> 3;
                    *(fp16x8*)&Gl[r * CIN + ((ch ^ (r & GSM)) << 3)] = v;
                }
            }
        }

        #pragma unroll
        for (int half = 0; half < 2; ++half) {
            __syncthreads();   // Gl ready / previous half's MFMA done with Wt
            // stage Wt for this half (rows half*128 .. half*128+127)
            for (int i = tid; i < 128 * GCHK; i += 256) {
                int row = i / GCHK, ch = i % GCHK;
                fp16x8 v = *(const fp16x8*)
                    &Wk[(size_t)(half * 128 + row) * CIN + ch * 8];
                *(fp16x8*)&Wt[row * CIN + ((ch ^ (row & GSM)) << 3)] = v;
            }
            __syncthreads();

            f32x4 acc[NCF];
            #pragma unroll
            for (int cf = 0; cf < NCF; ++cf)
                acc[cf] = (f32x4){0.f, 0.f, 0.f, 0.f};

            #pragma unroll
            for (int kk = 0; kk < NK; ++kk) {
                int col = kk * 32 + lk8;
                int r = wave * 16 + lrow;
                fp16x8 afr = *(const fp16x8*)
                    &Gl[r * CIN + ((((col >> 3) ^ (r & GSM))) << 3)];
                #pragma unroll
                for (int cf = 0; cf < NCF; ++cf) {
                    int rw = cf * 16 + lrow;
                    fp16x8 bfr = *(const fp16x8*)
                        &Wt[rw * CIN + ((((col >> 3) ^ (rw & GSM))) << 3)];
                    acc[cf] = __builtin_amdgcn_mfma_f32_16x16x32_f16(
                        afr, bfr, acc[cf], 0, 0, 0);
                }
            }

            // epilogue: scatter 256-wide rows via sslot
            int prb = wave * 16 + (lane >> 4) * 4;
            #pragma unroll
            for (int b = 0; b < 4; ++b) {
                int pr = prb + b;
                if (base + pr < M) {
                    size_t s = (size_t)sslot[pr];
                    #pragma unroll
                    for (int cf = 0; cf < NCF; ++cf)
                        contrib[s * 256 + half * 128 + cf * 16 + lrow] =
                            __float2half(acc[cf][b]);
                }
            }
        }
        __syncthreads();
    }
}

// ---------------- Phase B: scalar segmented sum, 4-deep load batching ----
// One channel per thread (r12 lesson: V=4 channel-vectorization HURT).
// The slot loop batches 4 INDEPENDENT loads per waitcnt (predicated tail)
// — r13's serial load->add chain paid full memory latency per slot
// (conv1: 25 slots/item; measured 1.2TB/s on a streaming read).
// OUT16=1: fp16 out; 0: fp32. PARTIN=1: accum from fp16 partial part_in.
template <int CSTR, bool STATS, int OUT16, int PARTIN>
__global__ __launch_bounds__(256) void phaseB8(
    const __half* __restrict__ contrib, const int* __restrict__ ptr,
    void* __restrict__ out_, const __half* __restrict__ part_in,
    int n, int ostr, int accum,
    double* __restrict__ statsbuf, int sqoff)
{
    float s1 = 0.f, s2 = 0.f;
    int total = n * CSTR;
    for (int idx = blockIdx.x * 256 + threadIdx.x; idx < total;
         idx += gridDim.x * 256) {
        int o = idx / CSTR, c = idx % CSTR;
        int a = ptr[o], b = ptr[o + 1];
        size_t oi = (size_t)o * ostr + c;
        float acc;
        if (accum) {
            if (PARTIN)
                acc = __half2float(part_in[(size_t)o * CSTR + c]);
            else if (OUT16)
                acc = __half2float(((const __half*)out_)[oi]);
            else
                acc = ((const float*)out_)[oi];
        } else {
            acc = 0.f;
        }
        for (int s = a; s < b; s += 4) {
            float v0 = __half2float(contrib[(size_t)s * CSTR + c]);
            float v1 = (s + 1 < b)
                ? __half2float(contrib[(size_t)(s + 1) * CSTR + c]) : 0.f;
            float v2 = (s + 2 < b)
                ? __half2float(contrib[(size_t)(s + 2) * CSTR + c]) : 0.f;
            float v3 = (s + 3 < b)
                ? __half2float(contrib[(size_t)(s + 3) * CSTR + c]) : 0.f;
            acc += ((v0 + v1) + (v2 + v3));
        }
        if (OUT16) ((__half*)out_)[oi] = __float2half(acc);
        else       ((float*)out_)[oi] = acc;
        if (STATS) { s1 += acc; s2 += acc * acc; }
    }
    if constexpr (STATS) {
        __shared__ double l1[256], l2[256];
        l1[threadIdx.x] = (double)s1; l2[threadIdx.x] = (double)s2;
        __syncthreads();
        for (int off = 128; off >= CSTR; off >>= 1) {
            if (threadIdx.x < (unsigned)off) {
                l1[threadIdx.x] += l1[threadIdx.x + off];
                l2[threadIdx.x] += l2[threadIdx.x + off];
            }
            __syncthreads();
        }
        if (threadIdx.x < CSTR) {
            atomicAdd(&statsbuf[threadIdx.x], l1[threadIdx.x]);
            atomicAdd(&statsbuf[sqoff + threadIdx.x], l2[threadIdx.x]);
        }
    }
}

// ---------------- BN helpers (fp64 stats) ----------------
template <int C>
__global__ __launch_bounds__(256) void make_scsh(
    const double* __restrict__ sums, const float* __restrict__ g,
    const float* __restrict__ b, float* __restrict__ sc, float* __restrict__ sh,
    double inv_n)
{
    int c = threadIdx.x;
    if (c < C) {
        double mean = sums[c] * inv_n;
        double var  = sums[C + c] * inv_n - mean * mean;
        float s = g[c] * (float)(1.0 / sqrt(var + (double)EPSc));
        sc[c] = s;
        sh[c] = b[c] - (float)mean * s;
    }
}

template <int C>
__global__ __launch_bounds__(256) void bn_apply_relu_kernel(
    float* __restrict__ x, int n, const double* __restrict__ sums,
    const float* __restrict__ g, const float* __restrict__ b)
{
    const int c = threadIdx.x % C;
    const double inv_n = 1.0 / (double)n;
    double mean = sums[c] * inv_n;
    double var  = sums[C + c] * inv_n - mean * mean;
    float scale = g[c] * (float)(1.0 / sqrt(var + (double)EPSc));
    float shift = b[c] - (float)mean * scale;
    size_t total = (size_t)n * C;
    size_t stride = (size_t)gridDim.x * 256;
    for (size_t i = (size_t)blockIdx.x * 256 + threadIdx.x; i < total; i += stride)
        x[i] = fmaxf(x[i] * scale + shift, 0.f);
}

// Variant that also writes an fp16 shadow copy (for the next layer's gather).
template <int C>
__global__ __launch_bounds__(256) void bn_apply_relu_shadow_kernel(
    float* __restrict__ x, __half* __restrict__ xh, int n,
    const double* __restrict__ sums,
    const float* __restrict__ g, const float* __restrict__ b)
{
    const int c = threadIdx.x % C;
    const double inv_n = 1.0 / (double)n;
    double mean = sums[c] * inv_n;
    double var  = sums[C + c] * inv_n - mean * mean;
    float scale = g[c] * (float)(1.0 / sqrt(var + (double)EPSc));
    float shift = b[c] - (float)mean * scale;
    size_t total = (size_t)n * C;
    size_t stride = (size_t)gridDim.x * 256;
    for (size_t i = (size_t)blockIdx.x * 256 + threadIdx.x; i < total; i += stride) {
        float v = fmaxf(x[i] * scale + shift, 0.f);
        x[i] = v;
        xh[i] = __float2half(v);
    }
}

// ---------------- host-side helpers ----------------
struct Plan { int q, nch; };

static Plan make_plan(long long tot_elems, int K, long long cap, int maxch)
{
    if (cap < 1) cap = 1;
    long long nch0 = (tot_elems + cap - 1) / cap;
    if (nch0 < 1) nch0 = 1;
    if (nch0 > K) nch0 = K;
    int q = (int)((K + nch0 - 1) / nch0);
    int nch = (K + q - 1) / q;
    if (nch > maxch) { q = (K + maxch - 1) / maxch; nch = (K + q - 1) / q; }
    return { q, nch };
}

static void build_csr2d(const int* iout, int* rank, int* bins, int* ptr, int* bsums,
                        int E, int M, int q, int nch, int stride, hipStream_t s)
{
    hipMemsetAsync(bins, 0, (size_t)nch * stride * sizeof(int), s);
    int gb = std::min(2048, (E + 255) / 256);
    hipLaunchKernelGGL(rank2d_kernel, dim3(gb), dim3(256), 0, s, iout, rank, bins, E, M, q, stride);
    int totalbins = nch * stride, nb = totalbins / 1024, bpc = stride / 1024;
    hipLaunchKernelGGL(scan1, dim3(nb), dim3(256), 0, s, bins, ptr, bsums, totalbins);
    hipLaunchKernelGGL(scan2s, dim3(1), dim3(64), 0, s, bsums, bpc, nch);
    hipLaunchKernelGGL(scan3, dim3(nb), dim3(256), 0, s, ptr, bsums, totalbins);
}

// One full layer (no cout split): k-chunked as needed.
template <int CIN, int COUT, int GMODE, bool STATS, int IN16, int OUT16>
static void run_layer(const void* feats, const float* W,
                      const int* iin, const int* iout, void* outp,
                      int M, int K, int n_out, int stride, int maxch,
                      int* bins, int* ptr, int* bsums, int* rank, __half* contrib,
                      _Float16* wh, long long cap_f32,
                      const float* sc, const float* sh,
                      double* statsbuf, hipStream_t s)
{
    int wtot = K * COUT * CIN;
    hipLaunchKernelGGL(wconv_fp16, dim3(std::min(2048, (wtot + 255) / 256)),
                       dim3(256), 0, s, W, wh, K, CIN, COUT, COUT, wtot);
    long long cap_h = cap_f32 * 2;
    Plan pl = make_plan((long long)K * M * COUT, K, cap_h, maxch);
    build_csr2d(iout, rank, bins, ptr, bsums, K * M, M, pl.q, pl.nch, stride, s);
    for (int ch = 0; ch < pl.nch; ++ch) {
        int k0 = ch * pl.q;
        int qc = std::min(pl.q, K - k0);
        dim3 g((M + 63) / 64, qc);
        hipLaunchKernelGGL((phaseA_mfma<CIN, COUT, GMODE, IN16>), g, dim3(256), 0, s,
                           feats, wh + (size_t)k0 * COUT * CIN,
                           iin + (size_t)k0 * M, iout + (size_t)k0 * M,
                           ptr + (size_t)ch * stride, rank + (size_t)k0 * M,
                           contrib, M, sc, sh);
        bool last = (ch == pl.nch - 1);
        if (STATS && last)
            hipLaunchKernelGGL((phaseB8<COUT, true, OUT16, 0>), dim3(2048), dim3(256), 0, s,
                               contrib, ptr + (size_t)ch * stride, outp,
                               (const __half*)nullptr, n_out, COUT,
                               ch ? 1 : 0, statsbuf, COUT);
        else
            hipLaunchKernelGGL((phaseB8<COUT, false, OUT16, 0>), dim3(2048), dim3(256), 0, s,
                               contrib, ptr + (size_t)ch * stride, outp,
                               (const __half*)nullptr, n_out, COUT,
                               ch ? 1 : 0, (double*)nullptr, 0);
    }
}

extern "C" void kernel_launch(void* const* d_in, const int* in_sizes, int n_in,
                              void* d_out, int out_size, void* d_ws, size_t ws_size,
                              hipStream_t stream)
{
    const float* x_feats = (const float*)d_in[0];
    const float* w1a = (const float*)d_in[1];
    const float* w1b = (const float*)d_in[2];
    const float* w1c = (const float*)d_in[3];
    const float* w2  = (const float*)d_in[4];
    const float* w3a = (const float*)d_in[5];
    const float* w3b = (const float*)d_in[6];
    const float* bn1b_g = (const float*)d_in[7];
    const float* bn1b_b = (const float*)d_in[8];
    const float* bn1c_g = (const float*)d_in[9];
    const float* bn1c_b = (const float*)d_in[10];
    const float* bn3a_g = (const float*)d_in[11];
    const float* bn3a_b = (const float*)d_in[12];
    const float* bn3b_g = (const float*)d_in[13];
    const float* bn3b_b = (const float*)d_in[14];
    const int* km1a_in  = (const int*)d_in[15];
    const int* km1a_out = (const int*)d_in[16];
    const int* km1b_in  = (const int*)d_in[17];
    const int* km1b_out = (const int*)d_in[18];
    const int* km1c_in  = (const int*)d_in[19];
    const int* km1c_out = (const int*)d_in[20];
    const int* km2_in   = (const int*)d_in[21];
    const int* km2_out  = (const int*)d_in[22];
    const int* km3a_in  = (const int*)d_in[23];
    const int* km3a_out = (const int*)d_in[24];
    const int* km3b_in  = (const int*)d_in[25];
    const int* km3b_out = (const int*)d_in[26];

    float* out  = (float*)d_out;
    float* x_e1 = out;                       // [N1,32] fp32 (final)
    float* x_e2 = out + (size_t)N1c * 32;    // [N2,256] fp32 (final)

    // ---- workspace layout (float-element offsets, 16B-aligned) ----
    float* ws = (float*)d_ws;
    float*  poolA  = ws;                        // 10,240,000 (h1 -> h3, fp16)
    float*  poolB  = poolA + 10240000;          //  5,120,000 (h2 -> h2b+xe1h)
    double* dstats = (double*)(poolB + 5120000);//  2,048 doubles
    float*  scsh   = (float*)(dstats + 2048);   //  1,024
    int*    bins   = (int*)(scsh + 1024);       //  819,200
    int*    ptr    = bins + 819200;             //  819,200
    int*    bsums  = ptr + 819200;              //  1,024
    int*    rank   = bsums + 1024;              //  2,500,000
    float*  whf    = (float*)(rank + 2500000);  //  442,400 (fp16 W^T buffer)
    _Float16* wh   = (_Float16*)whf;
    float*  contribf = whf + 442400;
    __half* contrib  = (__half*)contribf;
    const long long FIXED = 10240000LL + 5120000 + 4096 + 1024
                          + 819200 + 819200 + 1024 + 2500000 + 442400;
    long long cap = (long long)(ws_size / 4) - FIXED - 32;   // fp32 elems left
    if (cap < 1) cap = 1;

    __half* h1  = (__half*)poolA;   // [N1,32] fp16
    __half* h3  = (__half*)poolA;   // [N2,128] fp16 = poolA floats [0,5.12M)
    __half* h2  = (__half*)poolB;   // [N1,32] fp16
    __half* h2b = (__half*)poolB;   // [N2,64] fp16 (h2 dead by then)
    __half* xe1h = (__half*)poolB + 5120000;  // [N1,32] fp16 shadow of x_e1
    // conv3b partial buffer: 80000*256 fp16 = 20.48M halfs = 10.24M floats,
    // overlaid on poolA floats [5.12M,10.24M) + all of poolB — all dead by
    // conv3b (h1/h2/h2b/xe1h consumed; h3 occupies only poolA [0,5.12M)).
    __half* xpart = (__half*)(poolA + 5120000);

    double* dst1b = dstats;
    double* dst1c = dstats + 512;
    double* dst3a = dstats + 1024;
    double* dst3b = dstats + 1536;
    float* sc1b = scsh,       *sh1b = scsh + 32;
    float* sc3a = scsh + 256, *sh3a = scsh + 384;

    hipMemsetAsync(dstats, 0, 2048 * sizeof(double), stream);

    // ---- conv1a (1->32, K=125) + ReLU: scatter (val,k) + W-in-LDS reduce ----
    {
        build_csr2d(km1a_out, rank, bins, ptr, bsums, 125 * 20000, 20000, 125, 1,
                    STRIDE_N1, stream);
        hipLaunchKernelGGL(scatter_1a, dim3(2048), dim3(256), 0, stream,
                           x_feats, km1a_in, km1a_out, ptr, rank, (float2*)contribf,
                           125 * 20000, 20000);
        hipLaunchKernelGGL(phaseB_1a, dim3(2048), dim3(256), 0, stream,
                           (const float2*)contribf, ptr, w1a, h1, N1c);
    }

    // ---- conv1b (32->32, K=125): fp16 in/out + fp64 stats; BN fused later ----
    run_layer<32, 32, 0, true, 1, 1>(h1, w1b, km1b_in, km1b_out, h2, 20000, 125, N1c,
                                     STRIDE_N1, 8, bins, ptr, bsums, rank, contrib,
                                     wh, cap, nullptr, nullptr, dst1b, stream);
    hipLaunchKernelGGL((make_scsh<32>), dim3(1), dim3(256), 0, stream,
                       dst1b, bn1b_g, bn1b_b, sc1b, sh1b, 1.0 / N1c);

    // ---- conv1c (32->32, K=125): BN(h2)+ReLU at gather; x_e1 fp32 + stats ----
    run_layer<32, 32, 2, true, 1, 0>(h2, w1c, km1c_in, km1c_out, x_e1, 20000, 125, N1c,
                                     STRIDE_N1, 8, bins, ptr, bsums, rank, contrib,
                                     wh, cap, sc1b, sh1b, dst1c, stream);
    // BN+ReLU on x_e1 (final fp32) + fp16 shadow for conv2's gather
    hipLaunchKernelGGL((bn_apply_relu_shadow_kernel<32>), dim3(2048), dim3(256), 0, stream,
                       x_e1, xe1h, N1c, dst1c, bn1c_g, bn1c_b);

    // ---- conv2 (32->64, K=27): fp16 in (xe1h), fp16 out, no activation ----
    run_layer<32, 64, 0, false, 1, 1>(xe1h, w2, km2_in, km2_out, h2b, 30000, 27, N2c,
                                      STRIDE_N2, 10, bins, ptr, bsums, rank, contrib,
                                      wh, cap, nullptr, nullptr, nullptr, stream);

    // ---- conv3a (64->128, K=27): fp16 in/out + stats; BN fused at conv3b ----
    run_layer<64, 128, 0, true, 1, 1>(h2b, w3a, km3a_in, km3a_out, h3, 20000, 27, N2c,
                                      STRIDE_N2, 10, bins, ptr, bsums, rank, contrib,
                                      wh, cap, nullptr, nullptr, dst3a, stream);
    hipLaunchKernelGGL((make_scsh<128>), dim3(1), dim3(256), 0, stream,
                       dst3a, bn3a_g, bn3a_b, sc3a, sh3a, 1.0 / N2c);

    // ---- conv3b (128->256, K=27): dual-half phaseA (gather h3 once) ----
    // Multi-chunk phaseB accumulates through a fp16 partial (xpart).
    {
        const int M = 20000, K = 27;
        int wtot = K * 256 * 128;
        hipLaunchKernelGGL(wconv_fp16, dim3(2048), dim3(256), 0, stream,
                           w3b, wh, K, 128, 256, 256, wtot);
        Plan pl = make_plan((long long)K * M * 256, K, cap * 2, 10);
        build_csr2d(km3b_out, rank, bins, ptr, bsums, K * M, M, pl.q, pl.nch,
                    STRIDE_N2, stream);
        for (int ch = 0; ch < pl.nch; ++ch) {
            int k0 = ch * pl.q;
            int qc = std::min(pl.q, K - k0);
            dim3 g((M + 63) / 64, qc);
            hipLaunchKernelGGL((phaseA_mfma_3b<2>), g, dim3(256), 0, stream,
                               (const void*)h3, wh + (size_t)k0 * 256 * 128,
                               km3b_in + (size_t)k0 * M, km3b_out + (size_t)k0 * M,
                               ptr + (size_t)ch * STRIDE_N2, rank + (size_t)k0 * M,
                               contrib, M, sc3a, sh3a);
            bool last = (ch == pl.nch - 1);
            if (!last)
                hipLaunchKernelGGL((phaseB8<256, false, 1, 0>), dim3(2048), dim3(256), 0, stream,
                                   contrib, ptr + (size_t)ch * STRIDE_N2,
                                   xpart, (const __half*)nullptr, N2c, 256,
                                   ch ? 1 : 0, (double*)nullptr, 0);
            else if (ch == 0)
                hipLaunchKernelGGL((phaseB8<256, true, 0, 0>), dim3(2048), dim3(256), 0, stream,
                                   contrib, ptr + (size_t)ch * STRIDE_N2,
                                   x_e2, (const __half*)nullptr, N2c, 256,
                                   0, dst3b, 256);
            else
                hipLaunchKernelGGL((phaseB8<256, true, 0, 1>), dim3(2048), dim3(256), 0, stream,
                                   contrib, ptr + (size_t)ch * STRIDE_N2,
                                   x_e2, xpart, N2c, 256,
                                   1, dst3b, 256);
        }
        hipLaunchKernelGGL((bn_apply_relu_kernel<256>), dim3(2048), dim3(256), 0, stream,
                           x_e2, N2c, dst3b, bn3b_g, bn3b_b);
    }
}